// Round 3
// baseline (1172.131 us; speedup 1.0000x reference)
//
#include <hip/hip_runtime.h>

typedef unsigned short u16;
typedef __attribute__((ext_vector_type(4)))  float f32x4;
typedef __attribute__((ext_vector_type(16))) float f32x16;
typedef __attribute__((ext_vector_type(8)))  short s16x8;   // 8 bf16 MFMA fragment
typedef __attribute__((ext_vector_type(4)))  unsigned short u16x4;

typedef const __attribute__((address_space(1))) void* gp1;
typedef __attribute__((address_space(3))) void* lp3;
#define GLOAD16(g, l) __builtin_amdgcn_global_load_lds((gp1)(g), (lp3)(l), 16, 0, 0)

__device__ __forceinline__ u16 f2bf(float f) {
    union { float f; unsigned u; } c; c.f = f;
    unsigned r = c.u + 0x7fffu + ((c.u >> 16) & 1u);   // RNE
    return (u16)(r >> 16);
}

// ---------------- fp32 -> bf16 cast (all 5 arrays, one launch) ----------------
__global__ void castall(const float* __restrict__ x,  const float* __restrict__ wq,
                        const float* __restrict__ wk, const float* __restrict__ wv,
                        const float* __restrict__ wp,
                        u16* __restrict__ xb,  u16* __restrict__ wqb, u16* __restrict__ wkb,
                        u16* __restrict__ wvb, u16* __restrict__ wpb) {
    int blk = blockIdx.x;
    const float* src; u16* dst; long off;
    if (blk < 2048) { src = x; dst = xb; off = (long)blk * 1024; }
    else {
        int w = (blk - 2048) >> 9, bb = (blk - 2048) & 511;
        src = (w == 0 ? wq : w == 1 ? wk : w == 2 ? wv : wp);
        dst = (w == 0 ? wqb : w == 1 ? wkb : w == 2 ? wvb : wpb);
        off = (long)bb * 1024;
    }
    long i = off + threadIdx.x * 4;
    f32x4 v = *(const f32x4*)(src + i);
    u16x4 o;
    o[0] = f2bf(v[0]); o[1] = f2bf(v[1]); o[2] = f2bf(v[2]); o[3] = f2bf(v[3]);
    *(u16x4*)(dst + i) = o;
}

// ---------------- QKV projection GEMM ----------------
// M=8192 (b*1024+s), N=6144 (w*2048 + h*256 + e), K=256.
// Q -> [B,H,S,256] linear bf16.
// K -> swizzled tile image: per bh, 32 tiles [32 rows(s)][256 cols(e)],
//      elem (r,c) at u16 idx r*256 + ((c&~7)^((r&7)<<3)) + (c&7).
// V -> PADDED tile image: per bh, 32 tiles [256 rows(e)][40 cols(j)], j<32 valid,
//      elem (e,j) at u16 idx e*40 + j. 80B rows -> bank-staggered, no swizzle.
__global__ __launch_bounds__(256) void qkv_gemm(
    const u16* __restrict__ xb,
    const u16* __restrict__ Wqb, const u16* __restrict__ Wkb, const u16* __restrict__ Wvb,
    const float* __restrict__ bq, const float* __restrict__ bk, const float* __restrict__ bv,
    u16* __restrict__ Qb, u16* __restrict__ Kimg, u16* __restrict__ Vimg)
{
    __shared__ u16 As[128 * 32];
    __shared__ u16 Bs[128 * 32];
    const int tid  = threadIdx.x;
    const int lane = tid & 63;
    const int li   = lane & 15, lg = lane >> 4;
    const int wave = tid >> 6;
    const int wr   = wave >> 1, wc = wave & 1;
    const int m0   = blockIdx.x * 128;
    const int n0g  = blockIdx.y * 128;
    const int w    = n0g >> 11;            // 0:Q 1:K 2:V
    const int h    = (n0g >> 8) & 7;
    const int e0   = n0g & 255;            // 0 or 128
    const u16* Wsel = (w == 0 ? Wqb : (w == 1 ? Wkb : Wvb)) + h * 65536;

    const int srow = tid >> 2;             // 0..63
    const int scol = (tid & 3) * 8;

    f32x4 acc[4][4] = {};

    for (int k0 = 0; k0 < 256; k0 += 32) {
        __syncthreads();
        #pragma unroll
        for (int i = 0; i < 2; ++i) {
            int row = i * 64 + srow;
            GLOAD16(&xb[(m0 + row) * 256 + k0 + scol],   &As[i * 2048 + tid * 8]);
            GLOAD16(&Wsel[(e0 + row) * 256 + k0 + scol], &Bs[i * 2048 + tid * 8]);
        }
        __syncthreads();
        s16x8 af[4], bf[4];
        #pragma unroll
        for (int mi = 0; mi < 4; ++mi)
            af[mi] = *(const s16x8*)&As[(wr * 64 + mi * 16 + li) * 32 + lg * 8];
        #pragma unroll
        for (int ni = 0; ni < 4; ++ni)
            bf[ni] = *(const s16x8*)&Bs[(wc * 64 + ni * 16 + li) * 32 + lg * 8];
        #pragma unroll
        for (int mi = 0; mi < 4; ++mi)
            #pragma unroll
            for (int ni = 0; ni < 4; ++ni)
                acc[mi][ni] = __builtin_amdgcn_mfma_f32_16x16x32_bf16(af[mi], bf[ni], acc[mi][ni], 0, 0, 0);
    }

    const int b  = m0 >> 10;
    const int s0 = m0 & 1023;
    if (w == 0) {
        const float* bp = bq + 256 * h;
        #pragma unroll
        for (int ni = 0; ni < 4; ++ni) {
            const int e = e0 + wc * 64 + ni * 16 + li;
            const float bias = bp[e];
            u16* obase = Qb + ((size_t)(b * 8 + h)) * 1024 * 256 + e;
            #pragma unroll
            for (int mi = 0; mi < 4; ++mi)
                #pragma unroll
                for (int r = 0; r < 4; ++r) {
                    int s = s0 + wr * 64 + mi * 16 + lg * 4 + r;
                    obase[(size_t)s * 256] = f2bf(acc[mi][ni][r] + bias);
                }
        }
    } else if (w == 1) {
        const float* bp = bk + 256 * h;
        u16* kb = Kimg + ((size_t)(b * 8 + h)) * 262144;
        #pragma unroll
        for (int ni = 0; ni < 4; ++ni) {
            const int e = e0 + wc * 64 + ni * 16 + li;
            const float bias = bp[e];
            #pragma unroll
            for (int mi = 0; mi < 4; ++mi)
                #pragma unroll
                for (int r = 0; r < 4; ++r) {
                    int s = s0 + wr * 64 + mi * 16 + lg * 4 + r;
                    int t = s >> 5, rr = s & 31;
                    size_t idx = (size_t)t * 8192 + rr * 256
                               + (((e & ~7) ^ ((rr & 7) << 3)) | (e & 7));
                    kb[idx] = f2bf(acc[mi][ni][r] + bias);
                }
        }
    } else {
        const float* bp = bv + 256 * h;
        u16* vb = Vimg + ((size_t)(b * 8 + h)) * 327680;
        #pragma unroll
        for (int ni = 0; ni < 4; ++ni) {
            const int e = e0 + wc * 64 + ni * 16 + li;
            const float bias = bp[e];
            #pragma unroll
            for (int mi = 0; mi < 4; ++mi) {
                int s = s0 + wr * 64 + mi * 16 + lg * 4;   // multiple of 4
                int t = s >> 5, cj = s & 31;
                size_t idx = (size_t)t * 10240 + e * 40 + cj;
                u16x4 pk;
                #pragma unroll
                for (int r = 0; r < 4; ++r) pk[r] = f2bf(acc[mi][ni][r] + bias);
                *(u16x4*)&vb[idx] = pk;
            }
        }
    }
}

// ---------------- flash attention ----------------
// R11: 256 blocks = 64 (b,h) * 4 q-blocks; 4 waves (256 thr); each wave owns
// 64 q-rows as TWO 32-row sets sharing every K/V fragment read.
//
// Rationale (R8/R9/R10 post-mortem): all schedules pinned at ~83us because
// per-CU LDS read traffic was the floor — every wave read the IDENTICAL
// K/V fragments (lane-only addressing), 256 b128-reads/iter/CU ~ 3900 cyc
// vs 2048 cyc MFMA. Two q-sets make each kf read feed 2 QK MFMAs and each
// vf read feed 2 PV MFMAs: LDS reads halve (128/iter/CU ~ 1800 cyc), MFMA
// unchanged (2048 cyc/SIMD/iter) -> MFMA-bound. TLP (1 wave/SIMD) is
// replaced by ILP: QK0/QK1 interleave, 32 indep PV chains, set1 MFMAs
// cover set0 softmax.
//
// Staging ledger = R10's verified double-buffer, verbatim:
//   K: prologue tiles 0,1. QK(i) reads kslot i&1. After barrier-B stage
//      K tile min(i+2,31) into kslot i&1. K-waves (tid<128, 8 loads/batch):
//      vmcnt(8) at top allows 1 newest batch -> tile i resident.
//   V: prologue tile 0. PV(i-1) reads vslot (i+1)&1. After barrier-B stage
//      V tile min(i+1,31) into vslot (i+1)&1. V-waves (tid>=128, 10
//      loads/batch): vmcnt(10) -> tile i-1 resident.
//   Epilogue PV(31): tile 31 in vslot 1 (staged end iter 30; iter-31 dup
//   went to slot 0); V-wave vmcnt(10) retires it.
// NEW: explicit vmcnt(0) fence after the 32 Q-frag global loads, before the
// prologue stages — guarantees Q loads never count against the ledger.
__device__ __forceinline__ void softmax_pack(
    f32x16& sacc, float& m_run, float& l_run, f32x16* oacc,
    int hi, s16x8& paA, s16x8& paB)
{
    const float C = 0.09016844f;       // log2(e)/sqrt(256)
    const float THR = 16.0f;           // defer-max threshold (raw S units)
    float pm;
    {   // tree max: dependent depth 4 instead of 16
        float t[8];
        #pragma unroll
        for (int r = 0; r < 8; ++r) t[r] = fmaxf(sacc[r], sacc[r + 8]);
        #pragma unroll
        for (int r = 0; r < 4; ++r) t[r] = fmaxf(t[r], t[r + 4]);
        t[0] = fmaxf(t[0], t[2]); t[1] = fmaxf(t[1], t[3]);
        pm = fmaxf(t[0], t[1]);
    }
    pm = fmaxf(pm, __shfl_xor(pm, 32));
    if (!__all(pm - m_run <= THR)) {   // rare
        const float mnew = fmaxf(m_run, pm);
        const float corr = __builtin_amdgcn_exp2f((m_run - mnew) * C);
        l_run *= corr;
        #pragma unroll
        for (int r = 0; r < 16; ++r) {
            float rc = __shfl(corr, (r & 3) + 8 * (r >> 2) + 4 * hi);
            #pragma unroll
            for (int et = 0; et < 8; ++et) oacc[et][r] *= rc;
        }
        m_run = mnew;
    }
    #pragma unroll
    for (int r = 0; r < 16; ++r)
        sacc[r] = __builtin_amdgcn_exp2f((sacc[r] - m_run) * C);
    float psum;
    {   // tree sum
        float s[8];
        #pragma unroll
        for (int r = 0; r < 8; ++r) s[r] = sacc[r] + sacc[r + 8];
        #pragma unroll
        for (int r = 0; r < 4; ++r) s[r] = s[r] + s[r + 4];
        psum = (s[0] + s[1]) + (s[2] + s[3]);
    }
    psum += __shfl_xor(psum, 32);
    l_run += psum;
    unsigned dwA[4], dwB[4];
    #pragma unroll
    for (int c = 0; c < 4; ++c) {
        asm("v_cvt_pk_bf16_f32 %0, %1, %2" : "=v"(dwA[c]) : "v"(sacc[4*c]),   "v"(sacc[4*c+1]));
        asm("v_cvt_pk_bf16_f32 %0, %1, %2" : "=v"(dwB[c]) : "v"(sacc[4*c+2]), "v"(sacc[4*c+3]));
    }
    {
        unsigned a0 = dwA[0], a1 = dwA[1], b0 = dwB[0], b1 = dwB[1];
        asm("v_permlane32_swap_b32 %0, %1" : "+v"(a0), "+v"(a1));
        asm("v_permlane32_swap_b32 %0, %1" : "+v"(b0), "+v"(b1));
        union { unsigned u[4]; s16x8 v; } pk;
        pk.u[0] = a0; pk.u[1] = b0; pk.u[2] = a1; pk.u[3] = b1;
        paA = pk.v;
    }
    {
        unsigned a0 = dwA[2], a1 = dwA[3], b0 = dwB[2], b1 = dwB[3];
        asm("v_permlane32_swap_b32 %0, %1" : "+v"(a0), "+v"(a1));
        asm("v_permlane32_swap_b32 %0, %1" : "+v"(b0), "+v"(b1));
        union { unsigned u[4]; s16x8 v; } pk;
        pk.u[0] = a0; pk.u[1] = b0; pk.u[2] = a1; pk.u[3] = b1;
        paB = pk.v;
    }
}

__global__ __launch_bounds__(256, 1) void attn(
    const u16* __restrict__ Qb, const u16* __restrict__ Kimg,
    const u16* __restrict__ Vimg, u16* __restrict__ Ob)
{
    __shared__ u16 kbuf[2][8192];      // [32 j][256 d] swizzled, 16KB each
    __shared__ u16 vbuf[2][10240];     // [256 e][40 j] padded, 20KB each
    const int tid  = threadIdx.x;
    const int lane = tid & 63;
    const int wave = tid >> 6;         // 0..3
    const int col  = lane & 31;        // q-row (within set) for S, e-col for O
    const int hi   = lane >> 5;
    const int hi8  = hi * 8;
    const int ksw  = (lane & 7) << 3;  // K-read XOR swizzle
    // XCD swizzle: 256 blocks, 32 per XCD -> 8 distinct (b,h) per XCD
    const int bid  = ((blockIdx.x & 7) << 5) | (blockIdx.x >> 3);
    const int bh   = bid >> 2;
    const int qblk = bid & 3;
    const int q0   = qblk * 256 + wave * 64;   // wave's 64 q-rows (2 sets of 32)

    const u16* qp = Qb + ((size_t)bh * 1024 + q0) * 256;
    const u16* kg = Kimg + (size_t)bh * 262144;
    const u16* vg = Vimg + (size_t)bh * 327680;

    // role-split staging: waves 0-1 -> K (8 loads/batch), 2-3 -> V (10 loads/batch)
    #define STAGEK(sl, t)                                                         \
        {                                                                         \
            const int s_ = (sl), t_ = (t);                                        \
            const size_t kb_ = (size_t)t_ * 8192 + tid * 8;                       \
            _Pragma("unroll")                                                     \
            for (int c_ = 0; c_ < 8; ++c_)                                        \
                GLOAD16(&kg[kb_ + c_ * 1024], &kbuf[s_][c_ * 1024 + tid * 8]);    \
        }
    #define STAGEV(sl, t)                                                         \
        {                                                                         \
            const int s_ = (sl), t_ = (t);                                        \
            const int vth_ = tid - 128;                                           \
            const size_t vb_ = (size_t)t_ * 10240 + vth_ * 8;                     \
            _Pragma("unroll")                                                     \
            for (int c_ = 0; c_ < 10; ++c_)                                       \
                GLOAD16(&vg[vb_ + c_ * 1024], &vbuf[s_][c_ * 1024 + vth_ * 8]);   \
        }

    // Q B-frags for both sets (64 VGPR each)
    s16x8 qf0[16], qf1[16];
    #pragma unroll
    for (int dk = 0; dk < 16; ++dk) {
        qf0[dk] = *(const s16x8*)&qp[(size_t)col * 256 + dk * 16 + hi8];
        qf1[dk] = *(const s16x8*)&qp[(size_t)(32 + col) * 256 + dk * 16 + hi8];
    }
    // fence: retire ALL Q loads before the counted staging ledger begins
    asm volatile("s_waitcnt vmcnt(0)" ::: "memory");

    // prologue: K tiles 0,1; V tile 0 (V is consumed one iter later)
    if (tid < 128) { STAGEK(0, 0); STAGEK(1, 1); }
    else           { STAGEV(0, 0); }

    f32x16 oacc0[8] = {}, oacc1[8] = {};   // O[q=crow(r,hi)][e=et*32+col]
    float m0r = -1e30f, l0r = 0.f, m1r = -1e30f, l1r = 0.f;
    s16x8 paA0 = {}, paB0 = {}, paA1 = {}, paB1 = {};

    for (int i = 0; i < 32; ++i) {
        // counted wait: K-waves force tile i (QK), V-waves force tile i-1 (PV)
        if (tid < 128) { asm volatile("s_waitcnt vmcnt(8)"  ::: "memory"); }
        else           { asm volatile("s_waitcnt vmcnt(10)" ::: "memory"); }
        __builtin_amdgcn_s_barrier();              // barrier-A
        asm volatile("" ::: "memory");
        const u16* kt = kbuf[i & 1];               // K tile i
        const u16* vt = vbuf[(i + 1) & 1];         // V tile i-1

        f32x16 s0 = (f32x16){}, s1 = (f32x16){};
        __builtin_amdgcn_s_setprio(1);
        {   // QK(i) both sets: one kf read feeds 2 MFMAs
            const int rb_ = col * 256;
            #pragma unroll
            for (int dk = 0; dk < 16; ++dk) {
                s16x8 kf = *(const s16x8*)&kt[rb_ + ((dk * 16 + hi8) ^ ksw)];
                s0 = __builtin_amdgcn_mfma_f32_32x32x16_bf16(kf, qf0[dk], s0, 0, 0, 0);
                s1 = __builtin_amdgcn_mfma_f32_32x32x16_bf16(kf, qf1[dk], s1, 0, 0, 0);
            }
        }
        if (i > 0) {   // PV(i-1) both sets: one vf read feeds 2 MFMAs
            #pragma unroll
            for (int et = 0; et < 8; ++et) {
                s16x8 vf = *(const s16x8*)&vt[(et * 32 + col) * 40 + hi8];
                oacc0[et] = __builtin_amdgcn_mfma_f32_32x32x16_bf16(paA0, vf, oacc0[et], 0, 0, 0);
                oacc1[et] = __builtin_amdgcn_mfma_f32_32x32x16_bf16(paA1, vf, oacc1[et], 0, 0, 0);
            }
            #pragma unroll
            for (int et = 0; et < 8; ++et) {
                s16x8 vf = *(const s16x8*)&vt[(et * 32 + col) * 40 + 16 + hi8];
                oacc0[et] = __builtin_amdgcn_mfma_f32_32x32x16_bf16(paB0, vf, oacc0[et], 0, 0, 0);
                oacc1[et] = __builtin_amdgcn_mfma_f32_32x32x16_bf16(paB1, vf, oacc1[et], 0, 0, 0);
            }
        }
        __builtin_amdgcn_s_setprio(0);

        softmax_pack(s0, m0r, l0r, oacc0, hi, paA0, paB0);   // WAR: pa consumed above
        softmax_pack(s1, m1r, l1r, oacc1, hi, paA1, paB1);

        asm volatile("" ::: "memory");
        __builtin_amdgcn_s_barrier();              // barrier-B: slot reads done
        asm volatile("" ::: "memory");
        const int ktile = (i + 2 < 32) ? (i + 2) : 31;   // clamp keeps count invariant
        const int vtile = (i + 1 < 32) ? (i + 1) : 31;
        if (tid < 128) { STAGEK(i & 1, ktile); }         // kslot i&1 just freed
        else           { STAGEV((i + 1) & 1, vtile); }   // vslot (i+1)&1 just freed
    }
    #undef STAGEK
    #undef STAGEV

    // epilogue: PV(31), both sets. V tile 31 is in vslot 1.
    if (tid >= 128) { asm volatile("s_waitcnt vmcnt(10)" ::: "memory"); }
    __builtin_amdgcn_s_barrier();
    asm volatile("" ::: "memory");
    {
        const u16* vt = vbuf[1];
        __builtin_amdgcn_s_setprio(1);
        #pragma unroll
        for (int et = 0; et < 8; ++et) {
            s16x8 vf = *(const s16x8*)&vt[(et * 32 + col) * 40 + hi8];
            oacc0[et] = __builtin_amdgcn_mfma_f32_32x32x16_bf16(paA0, vf, oacc0[et], 0, 0, 0);
            oacc1[et] = __builtin_amdgcn_mfma_f32_32x32x16_bf16(paA1, vf, oacc1[et], 0, 0, 0);
        }
        #pragma unroll
        for (int et = 0; et < 8; ++et) {
            s16x8 vf = *(const s16x8*)&vt[(et * 32 + col) * 40 + 16 + hi8];
            oacc0[et] = __builtin_amdgcn_mfma_f32_32x32x16_bf16(paB0, vf, oacc0[et], 0, 0, 0);
            oacc1[et] = __builtin_amdgcn_mfma_f32_32x32x16_bf16(paB1, vf, oacc1[et], 0, 0, 0);
        }
        __builtin_amdgcn_s_setprio(0);
    }

    // normalize + store both sets: Ob [B,S,H*256]
    const int b = bh >> 3, h = bh & 7;
    u16* op = Ob + ((size_t)b * 1024) * 2048 + h * 256;
    {
        const float linv = 1.0f / l0r;
        #pragma unroll
        for (int r = 0; r < 16; ++r) {
            const int crow = (r & 3) + 8 * (r >> 2) + 4 * hi;
            float lr = __shfl(linv, crow);
            const size_t row = q0 + crow;
            #pragma unroll
            for (int et = 0; et < 8; ++et)
                op[row * 2048 + et * 32 + col] = f2bf(oacc0[et][r] * lr);
        }
    }
    {
        const float linv = 1.0f / l1r;
        #pragma unroll
        for (int r = 0; r < 16; ++r) {
            const int crow = (r & 3) + 8 * (r >> 2) + 4 * hi;
            float lr = __shfl(linv, crow);
            const size_t row = q0 + 32 + crow;
            #pragma unroll
            for (int et = 0; et < 8; ++et)
                op[row * 2048 + et * 32 + col] = f2bf(oacc1[et][r] * lr);
        }
    }
}

// ---------------- output projection ----------------
// out[m, n] = sum_k Ob[m, k] * Wp[n, k]; M=8192, N=256, K=2048; fp32 out.
// BM=32, BN=128 -> grid 512 blocks (2 per CU). (R5 known-good version.)
__global__ __launch_bounds__(256) void out_gemm(
    const u16* __restrict__ Ob, const u16* __restrict__ Wpb, float* __restrict__ out)
{
    __shared__ u16 As[32 * 32];
    __shared__ u16 Bs[128 * 32];
    const int tid  = threadIdx.x;
    const int lane = tid & 63;
    const int li   = lane & 15, lg = lane >> 4;
    const int wave = tid >> 6;
    const int wr   = wave >> 1, wc = wave & 1;   // wave tile 16x64
    const int m0   = blockIdx.x * 32;
    const int n0   = blockIdx.y * 128;
    const int srow = tid >> 2;                   // 0..63
    const int scol = (tid & 3) * 8;

    f32x4 acc[4] = {};

    for (int k0 = 0; k0 < 2048; k0 += 32) {
        __syncthreads();
        if (tid < 128)
            GLOAD16(&Ob[(size_t)(m0 + srow) * 2048 + k0 + scol], &As[tid * 8]);
        #pragma unroll
        for (int i = 0; i < 2; ++i)
            GLOAD16(&Wpb[(size_t)(n0 + i * 64 + srow) * 2048 + k0 + scol],
                    &Bs[i * 2048 + tid * 8]);
        __syncthreads();
        s16x8 af, bf[4];
        af = *(const s16x8*)&As[(wr * 16 + li) * 32 + lg * 8];
        #pragma unroll
        for (int ni = 0; ni < 4; ++ni)
            bf[ni] = *(const s16x8*)&Bs[(wc * 64 + ni * 16 + li) * 32 + lg * 8];
        #pragma unroll
        for (int ni = 0; ni < 4; ++ni)
            acc[ni] = __builtin_amdgcn_mfma_f32_16x16x32_bf16(af, bf[ni], acc[ni], 0, 0, 0);
    }

    #pragma unroll
    for (int ni = 0; ni < 4; ++ni) {
        int n = n0 + wc * 64 + ni * 16 + li;
        #pragma unroll
        for (int r = 0; r < 4; ++r) {
            int m = m0 + wr * 16 + lg * 4 + r;
            out[(size_t)m * 256 + n] = acc[ni][r];
        }
    }
}

extern "C" void kernel_launch(void* const* d_in, const int* in_sizes, int n_in,
                              void* d_out, int out_size, void* d_ws, size_t ws_size,
                              hipStream_t stream) {
    const float* x  = (const float*)d_in[0];
    const float* Wq = (const float*)d_in[1];
    const float* Wk = (const float*)d_in[2];
    const float* Wv = (const float*)d_in[3];
    const float* bq = (const float*)d_in[4];
    const float* bk = (const float*)d_in[5];
    const float* bv = (const float*)d_in[6];
    const float* Wp = (const float*)d_in[7];
    float* out = (float*)d_out;

    u16* xb   = (u16*)d_ws;               // 2,097,152
    u16* Wqb  = xb   + (1u << 21);        // 524,288 each
    u16* Wkb  = Wqb  + (1u << 19);
    u16* Wvb  = Wkb  + (1u << 19);
    u16* Wpb  = Wvb  + (1u << 19);
    u16* Qb   = Wpb  + (1u << 19);        // 16,777,216
    u16* Kimg = Qb   + (1u << 24);        // 16,777,216
    u16* Vimg = Kimg + (1u << 24);        // 20,971,520 (padded V)
    u16* Ob   = Vimg + 20971520u;         // 16,777,216

    castall<<<4096, 256, 0, stream>>>(x, Wq, Wk, Wv, Wp, xb, Wqb, Wkb, Wvb, Wpb);
    qkv_gemm<<<dim3(64, 48), 256, 0, stream>>>(xb, Wqb, Wkb, Wvb, bq, bk, bv, Qb, Kimg, Vimg);
    attn<<<256, 256, 0, stream>>>(Qb, Kimg, Vimg, Ob);
    out_gemm<<<dim3(256, 2), 256, 0, stream>>>(Ob, Wpb, out);
}

// Round 4
// 226.794 us; speedup vs baseline: 5.1683x; 5.1683x over previous
//
#include <hip/hip_runtime.h>

typedef unsigned short u16;
typedef __attribute__((ext_vector_type(4)))  float f32x4;
typedef __attribute__((ext_vector_type(16))) float f32x16;
typedef __attribute__((ext_vector_type(8)))  short s16x8;   // 8 bf16 MFMA fragment
typedef __attribute__((ext_vector_type(4)))  unsigned short u16x4;

typedef const __attribute__((address_space(1))) void* gp1;
typedef __attribute__((address_space(3))) void* lp3;
#define GLOAD16(g, l) __builtin_amdgcn_global_load_lds((gp1)(g), (lp3)(l), 16, 0, 0)

__device__ __forceinline__ u16 f2bf(float f) {
    union { float f; unsigned u; } c; c.f = f;
    unsigned r = c.u + 0x7fffu + ((c.u >> 16) & 1u);   // RNE
    return (u16)(r >> 16);
}

// ---------------- fp32 -> bf16 cast (all 5 arrays, one launch) ----------------
__global__ void castall(const float* __restrict__ x,  const float* __restrict__ wq,
                        const float* __restrict__ wk, const float* __restrict__ wv,
                        const float* __restrict__ wp,
                        u16* __restrict__ xb,  u16* __restrict__ wqb, u16* __restrict__ wkb,
                        u16* __restrict__ wvb, u16* __restrict__ wpb) {
    int blk = blockIdx.x;
    const float* src; u16* dst; long off;
    if (blk < 2048) { src = x; dst = xb; off = (long)blk * 1024; }
    else {
        int w = (blk - 2048) >> 9, bb = (blk - 2048) & 511;
        src = (w == 0 ? wq : w == 1 ? wk : w == 2 ? wv : wp);
        dst = (w == 0 ? wqb : w == 1 ? wkb : w == 2 ? wvb : wpb);
        off = (long)bb * 1024;
    }
    long i = off + threadIdx.x * 4;
    f32x4 v = *(const f32x4*)(src + i);
    u16x4 o;
    o[0] = f2bf(v[0]); o[1] = f2bf(v[1]); o[2] = f2bf(v[2]); o[3] = f2bf(v[3]);
    *(u16x4*)(dst + i) = o;
}

// ---------------- QKV projection GEMM ----------------
// M=8192 (b*1024+s), N=6144 (w*2048 + h*256 + e), K=256.
// Q -> [B,H,S,256] linear bf16.
// K -> swizzled tile image: per bh, 32 tiles [32 rows(s)][256 cols(e)],
//      elem (r,c) at u16 idx r*256 + ((c&~7)^((r&7)<<3)) + (c&7).
// V -> PADDED tile image: per bh, 32 tiles [256 rows(e)][40 cols(j)], j<32 valid,
//      elem (e,j) at u16 idx e*40 + j. 80B rows -> bank-staggered, no swizzle.
__global__ __launch_bounds__(256) void qkv_gemm(
    const u16* __restrict__ xb,
    const u16* __restrict__ Wqb, const u16* __restrict__ Wkb, const u16* __restrict__ Wvb,
    const float* __restrict__ bq, const float* __restrict__ bk, const float* __restrict__ bv,
    u16* __restrict__ Qb, u16* __restrict__ Kimg, u16* __restrict__ Vimg)
{
    __shared__ u16 As[128 * 32];
    __shared__ u16 Bs[128 * 32];
    const int tid  = threadIdx.x;
    const int lane = tid & 63;
    const int li   = lane & 15, lg = lane >> 4;
    const int wave = tid >> 6;
    const int wr   = wave >> 1, wc = wave & 1;
    const int m0   = blockIdx.x * 128;
    const int n0g  = blockIdx.y * 128;
    const int w    = n0g >> 11;            // 0:Q 1:K 2:V
    const int h    = (n0g >> 8) & 7;
    const int e0   = n0g & 255;            // 0 or 128
    const u16* Wsel = (w == 0 ? Wqb : (w == 1 ? Wkb : Wvb)) + h * 65536;

    const int srow = tid >> 2;             // 0..63
    const int scol = (tid & 3) * 8;

    f32x4 acc[4][4] = {};

    for (int k0 = 0; k0 < 256; k0 += 32) {
        __syncthreads();
        #pragma unroll
        for (int i = 0; i < 2; ++i) {
            int row = i * 64 + srow;
            GLOAD16(&xb[(m0 + row) * 256 + k0 + scol],   &As[i * 2048 + tid * 8]);
            GLOAD16(&Wsel[(e0 + row) * 256 + k0 + scol], &Bs[i * 2048 + tid * 8]);
        }
        __syncthreads();
        s16x8 af[4], bf[4];
        #pragma unroll
        for (int mi = 0; mi < 4; ++mi)
            af[mi] = *(const s16x8*)&As[(wr * 64 + mi * 16 + li) * 32 + lg * 8];
        #pragma unroll
        for (int ni = 0; ni < 4; ++ni)
            bf[ni] = *(const s16x8*)&Bs[(wc * 64 + ni * 16 + li) * 32 + lg * 8];
        #pragma unroll
        for (int mi = 0; mi < 4; ++mi)
            #pragma unroll
            for (int ni = 0; ni < 4; ++ni)
                acc[mi][ni] = __builtin_amdgcn_mfma_f32_16x16x32_bf16(af[mi], bf[ni], acc[mi][ni], 0, 0, 0);
    }

    const int b  = m0 >> 10;
    const int s0 = m0 & 1023;
    if (w == 0) {
        const float* bp = bq + 256 * h;
        #pragma unroll
        for (int ni = 0; ni < 4; ++ni) {
            const int e = e0 + wc * 64 + ni * 16 + li;
            const float bias = bp[e];
            u16* obase = Qb + ((size_t)(b * 8 + h)) * 1024 * 256 + e;
            #pragma unroll
            for (int mi = 0; mi < 4; ++mi)
                #pragma unroll
                for (int r = 0; r < 4; ++r) {
                    int s = s0 + wr * 64 + mi * 16 + lg * 4 + r;
                    obase[(size_t)s * 256] = f2bf(acc[mi][ni][r] + bias);
                }
        }
    } else if (w == 1) {
        const float* bp = bk + 256 * h;
        u16* kb = Kimg + ((size_t)(b * 8 + h)) * 262144;
        #pragma unroll
        for (int ni = 0; ni < 4; ++ni) {
            const int e = e0 + wc * 64 + ni * 16 + li;
            const float bias = bp[e];
            #pragma unroll
            for (int mi = 0; mi < 4; ++mi)
                #pragma unroll
                for (int r = 0; r < 4; ++r) {
                    int s = s0 + wr * 64 + mi * 16 + lg * 4 + r;
                    int t = s >> 5, rr = s & 31;
                    size_t idx = (size_t)t * 8192 + rr * 256
                               + (((e & ~7) ^ ((rr & 7) << 3)) | (e & 7));
                    kb[idx] = f2bf(acc[mi][ni][r] + bias);
                }
        }
    } else {
        const float* bp = bv + 256 * h;
        u16* vb = Vimg + ((size_t)(b * 8 + h)) * 327680;
        #pragma unroll
        for (int ni = 0; ni < 4; ++ni) {
            const int e = e0 + wc * 64 + ni * 16 + li;
            const float bias = bp[e];
            #pragma unroll
            for (int mi = 0; mi < 4; ++mi) {
                int s = s0 + wr * 64 + mi * 16 + lg * 4;   // multiple of 4
                int t = s >> 5, cj = s & 31;
                size_t idx = (size_t)t * 10240 + e * 40 + cj;
                u16x4 pk;
                #pragma unroll
                for (int r = 0; r < 4; ++r) pk[r] = f2bf(acc[mi][ni][r] + bias);
                *(u16x4*)&vb[idx] = pk;
            }
        }
    }
}

// ---------------- flash attention ----------------
// R12: revert to R9 geometry (256 blocks = 64 bh * 4 q-blocks; 8 waves/block;
// 32 q-rows/wave; 3-slot K + 3-slot V = 108KB LDS; 1 block/CU). R11's 64-row
// variant spilled (256+ unified regs -> 4.5GB scratch traffic).
//
// Two changes vs R9:
// 1. CROSS-ITER SOFTMAX PIPELINE: carry raw scores sprev across the barrier.
//    Iter i program order: SM(sprev=scores(i-1)) ; QK(i)->scur ; PV(i-1).
//    SM has no deps on QK -> scheduler interleaves its VALU under QK's
//    MFMA/ds_read stream; SM leaves the critical path. Register-safe: sprev
//    dies into paA/paB before scur peaks (~230 unified, fits 256 @ 2w/SIMD).
// 2. SINGLE barrier per iter. With 3 slots, the slot staged at top of iter i
//    was last READ in iter i-1, and every wave passed this barrier after
//    finishing iter i-1 -> stage-after-barrier is race-free. Stage issues
//    right after the barrier (earliest prefetch).
//
// Ledger (role-split: waves 0-3 stage K, 4 loads/batch; waves 4-7 stage V,
// 5 loads/batch; counted vmcnt BEFORE barrier allows exactly 1 newest batch):
//   K: prologue tiles 0,1 -> slots 0,1. Top of iter i: vmcnt(4) retires all
//      but the tile-(i+1) batch -> tile i resident; barrier publishes; stage
//      tile min(i+2,31) -> slot (i+2)%3 (last read iter i-1). QK reads slot
//      i%3; in-flight batch lands in (i+1)%3 -> all three distinct.
//   V: prologue tile 0 -> slot 0. vmcnt(5) -> tile i-1 resident; stage tile
//      min(i+1,31) -> slot (i+1)%3 (last read iter i-1, since PV(j-1) reads
//      slot (j-1)%3). PV(i-1) reads slot (i+2)%3.
//   Tail: clamped dup stages keep counts invariant; dups land in slots whose
//   reads are already complete. Epilogue: V-wave vmcnt(5) retires the iter-30
//   batch (tile 31 -> slot 1); barrier; SM(scores(31)); PV(31) from vslot 1.
// Q-frag loads fenced with vmcnt(0) before the prologue stages so they never
// count against the ledger.
__device__ __forceinline__ void softmax_pack(
    f32x16& sacc, float& m_run, float& l_run, f32x16* oacc,
    int hi, s16x8& paA, s16x8& paB)
{
    const float C = 0.09016844f;       // log2(e)/sqrt(256)
    const float THR = 16.0f;           // defer-max threshold (raw S units)
    float pm;
    {   // tree max: dependent depth 4 instead of 16
        float t[8];
        #pragma unroll
        for (int r = 0; r < 8; ++r) t[r] = fmaxf(sacc[r], sacc[r + 8]);
        #pragma unroll
        for (int r = 0; r < 4; ++r) t[r] = fmaxf(t[r], t[r + 4]);
        t[0] = fmaxf(t[0], t[2]); t[1] = fmaxf(t[1], t[3]);
        pm = fmaxf(t[0], t[1]);
    }
    pm = fmaxf(pm, __shfl_xor(pm, 32));
    if (!__all(pm - m_run <= THR)) {   // rare
        const float mnew = fmaxf(m_run, pm);
        const float corr = __builtin_amdgcn_exp2f((m_run - mnew) * C);
        l_run *= corr;
        #pragma unroll
        for (int r = 0; r < 16; ++r) {
            float rc = __shfl(corr, (r & 3) + 8 * (r >> 2) + 4 * hi);
            #pragma unroll
            for (int et = 0; et < 8; ++et) oacc[et][r] *= rc;
        }
        m_run = mnew;
    }
    #pragma unroll
    for (int r = 0; r < 16; ++r)
        sacc[r] = __builtin_amdgcn_exp2f((sacc[r] - m_run) * C);
    float psum;
    {   // tree sum
        float s[8];
        #pragma unroll
        for (int r = 0; r < 8; ++r) s[r] = sacc[r] + sacc[r + 8];
        #pragma unroll
        for (int r = 0; r < 4; ++r) s[r] = s[r] + s[r + 4];
        psum = (s[0] + s[1]) + (s[2] + s[3]);
    }
    psum += __shfl_xor(psum, 32);
    l_run += psum;
    unsigned dwA[4], dwB[4];
    #pragma unroll
    for (int c = 0; c < 4; ++c) {
        asm("v_cvt_pk_bf16_f32 %0, %1, %2" : "=v"(dwA[c]) : "v"(sacc[4*c]),   "v"(sacc[4*c+1]));
        asm("v_cvt_pk_bf16_f32 %0, %1, %2" : "=v"(dwB[c]) : "v"(sacc[4*c+2]), "v"(sacc[4*c+3]));
    }
    {
        unsigned a0 = dwA[0], a1 = dwA[1], b0 = dwB[0], b1 = dwB[1];
        asm("v_permlane32_swap_b32 %0, %1" : "+v"(a0), "+v"(a1));
        asm("v_permlane32_swap_b32 %0, %1" : "+v"(b0), "+v"(b1));
        union { unsigned u[4]; s16x8 v; } pk;
        pk.u[0] = a0; pk.u[1] = b0; pk.u[2] = a1; pk.u[3] = b1;
        paA = pk.v;
    }
    {
        unsigned a0 = dwA[2], a1 = dwA[3], b0 = dwB[2], b1 = dwB[3];
        asm("v_permlane32_swap_b32 %0, %1" : "+v"(a0), "+v"(a1));
        asm("v_permlane32_swap_b32 %0, %1" : "+v"(b0), "+v"(b1));
        union { unsigned u[4]; s16x8 v; } pk;
        pk.u[0] = a0; pk.u[1] = b0; pk.u[2] = a1; pk.u[3] = b1;
        paB = pk.v;
    }
}

__global__ __launch_bounds__(512, 2) void attn(
    const u16* __restrict__ Qb, const u16* __restrict__ Kimg,
    const u16* __restrict__ Vimg, u16* __restrict__ Ob)
{
    __shared__ u16 kbuf[3][8192];      // [32 j][256 d] swizzled, 16KB each
    __shared__ u16 vbuf[3][10240];     // [256 e][40 j] padded, 20KB each
    const int tid  = threadIdx.x;
    const int lane = tid & 63;
    const int wave = tid >> 6;
    const int col  = lane & 31;        // q-row for S, e-col for O
    const int hi   = lane >> 5;
    const int hi8  = hi * 8;
    const int ksw  = (lane & 7) << 3;  // K-read XOR swizzle
    // XCD swizzle: 256 blocks, 32 per XCD -> 8 distinct (b,h) per XCD
    const int bid  = ((blockIdx.x & 7) << 5) | (blockIdx.x >> 3);
    const int bh   = bid >> 2;
    const int qblk = bid & 3;
    const int q0   = qblk * 256 + wave * 32;   // wave's 32 q-rows

    const u16* qp = Qb + ((size_t)bh * 1024 + q0) * 256;
    const u16* kg = Kimg + (size_t)bh * 262144;
    const u16* vg = Vimg + (size_t)bh * 327680;

    // role-split staging: waves 0-3 -> K (4 loads/batch), 4-7 -> V (5 loads/batch)
    #define STAGEK(sl, t)                                                         \
        {                                                                         \
            const int s_ = (sl), t_ = (t);                                        \
            const size_t kb_ = (size_t)t_ * 8192 + tid * 8;                       \
            _Pragma("unroll")                                                     \
            for (int c_ = 0; c_ < 4; ++c_)                                        \
                GLOAD16(&kg[kb_ + c_ * 2048], &kbuf[s_][c_ * 2048 + tid * 8]);    \
        }
    #define STAGEV(sl, t)                                                         \
        {                                                                         \
            const int s_ = (sl), t_ = (t);                                        \
            const int vth_ = tid - 256;                                           \
            const size_t vb_ = (size_t)t_ * 10240 + vth_ * 8;                     \
            _Pragma("unroll")                                                     \
            for (int c_ = 0; c_ < 5; ++c_)                                        \
                GLOAD16(&vg[vb_ + c_ * 2048], &vbuf[s_][c_ * 2048 + vth_ * 8]);   \
        }

    // Q B-frags first, then fence so they never count against the ledger
    s16x8 qf[16];
    #pragma unroll
    for (int dk = 0; dk < 16; ++dk)
        qf[dk] = *(const s16x8*)&qp[(size_t)col * 256 + dk * 16 + hi8];
    asm volatile("s_waitcnt vmcnt(0)" ::: "memory");

    // prologue: K tiles 0,1 -> slots 0,1; V tile 0 -> slot 0
    if (tid < 256) { STAGEK(0, 0); STAGEK(1, 1); }
    else           { STAGEV(0, 0); }

    f32x16 oacc[8] = {};               // O[q=crow(r,hi)][e=et*32+col]
    float m_run = -1e30f, l_run = 0.f;
    f32x16 sprev;                      // raw scores of tile i-1 (carried)
    s16x8 paA, paB;

    for (int i = 0; i < 32; ++i) {
        // counted wait: K-waves force tile i (QK), V-waves force tile i-1 (PV)
        if (tid < 256) { asm volatile("s_waitcnt vmcnt(4)" ::: "memory"); }
        else           { asm volatile("s_waitcnt vmcnt(5)" ::: "memory"); }
        __builtin_amdgcn_s_barrier();              // single barrier per iter
        asm volatile("" ::: "memory");

        // stage immediately (earliest prefetch; targets freed slots)
        const int ktile = (i + 2 < 32) ? (i + 2) : 31;
        const int vtile = (i + 1 < 32) ? (i + 1) : 31;
        if (tid < 256) { STAGEK((i + 2) % 3, ktile); }
        else           { STAGEV((i + 1) % 3, vtile); }

        const u16* kt = kbuf[i % 3];               // K tile i
        const u16* vt = vbuf[(i + 2) % 3];         // V tile i-1

        // SM(i-1): pure VALU, no deps on QK(i) -> hides under the MFMA stream
        if (i > 0)
            softmax_pack(sprev, m_run, l_run, oacc, hi, paA, paB);

        f32x16 scur = (f32x16){};
        __builtin_amdgcn_s_setprio(1);
        {   // QK(i): S[j=crow(r,hi)][q=col]
            const int rb_ = col * 256;
            #pragma unroll
            for (int dk = 0; dk < 16; ++dk) {
                s16x8 kf = *(const s16x8*)&kt[rb_ + ((dk * 16 + hi8) ^ ksw)];
                scur = __builtin_amdgcn_mfma_f32_32x32x16_bf16(kf, qf[dk], scur, 0, 0, 0);
            }
        }
        if (i > 0) {   // PV(i-1): needs paA/paB from SM(i-1)
            #pragma unroll
            for (int et = 0; et < 8; ++et) {
                s16x8 vf = *(const s16x8*)&vt[(et * 32 + col) * 40 + hi8];
                oacc[et] = __builtin_amdgcn_mfma_f32_32x32x16_bf16(paA, vf, oacc[et], 0, 0, 0);
            }
            #pragma unroll
            for (int et = 0; et < 8; ++et) {
                s16x8 vf = *(const s16x8*)&vt[(et * 32 + col) * 40 + 16 + hi8];
                oacc[et] = __builtin_amdgcn_mfma_f32_32x32x16_bf16(paB, vf, oacc[et], 0, 0, 0);
            }
        }
        __builtin_amdgcn_s_setprio(0);

        sprev = scur;                              // carry raw scores
        asm volatile("" ::: "memory");
    }
    #undef STAGEK
    #undef STAGEV

    // epilogue: SM(31) + PV(31). V tile 31 staged at iter 30 -> vslot 1.
    if (tid >= 256) { asm volatile("s_waitcnt vmcnt(5)" ::: "memory"); }
    __builtin_amdgcn_s_barrier();
    asm volatile("" ::: "memory");
    softmax_pack(sprev, m_run, l_run, oacc, hi, paA, paB);
    {
        const u16* vt = vbuf[1];
        __builtin_amdgcn_s_setprio(1);
        #pragma unroll
        for (int et = 0; et < 8; ++et) {
            s16x8 vf = *(const s16x8*)&vt[(et * 32 + col) * 40 + hi8];
            oacc[et] = __builtin_amdgcn_mfma_f32_32x32x16_bf16(paA, vf, oacc[et], 0, 0, 0);
        }
        #pragma unroll
        for (int et = 0; et < 8; ++et) {
            s16x8 vf = *(const s16x8*)&vt[(et * 32 + col) * 40 + 16 + hi8];
            oacc[et] = __builtin_amdgcn_mfma_f32_32x32x16_bf16(paB, vf, oacc[et], 0, 0, 0);
        }
        __builtin_amdgcn_s_setprio(0);
    }

    // normalize + store: Ob [B,S,H*256]
    const float linv = 1.0f / l_run;
    const int b = bh >> 3, h = bh & 7;
    u16* op = Ob + ((size_t)b * 1024) * 2048 + h * 256;
    #pragma unroll
    for (int r = 0; r < 16; ++r) {
        const int crow = (r & 3) + 8 * (r >> 2) + 4 * hi;
        float lr = __shfl(linv, crow);
        const size_t row = q0 + crow;
        #pragma unroll
        for (int et = 0; et < 8; ++et)
            op[row * 2048 + et * 32 + col] = f2bf(oacc[et][r] * lr);
    }
}

// ---------------- output projection ----------------
// out[m, n] = sum_k Ob[m, k] * Wp[n, k]; M=8192, N=256, K=2048; fp32 out.
// BM=32, BN=128 -> grid 512 blocks (2 per CU). (R5 known-good version.)
__global__ __launch_bounds__(256) void out_gemm(
    const u16* __restrict__ Ob, const u16* __restrict__ Wpb, float* __restrict__ out)
{
    __shared__ u16 As[32 * 32];
    __shared__ u16 Bs[128 * 32];
    const int tid  = threadIdx.x;
    const int lane = tid & 63;
    const int li   = lane & 15, lg = lane >> 4;
    const int wave = tid >> 6;
    const int wr   = wave >> 1, wc = wave & 1;   // wave tile 16x64
    const int m0   = blockIdx.x * 32;
    const int n0   = blockIdx.y * 128;
    const int srow = tid >> 2;                   // 0..63
    const int scol = (tid & 3) * 8;

    f32x4 acc[4] = {};

    for (int k0 = 0; k0 < 2048; k0 += 32) {
        __syncthreads();
        if (tid < 128)
            GLOAD16(&Ob[(size_t)(m0 + srow) * 2048 + k0 + scol], &As[tid * 8]);
        #pragma unroll
        for (int i = 0; i < 2; ++i)
            GLOAD16(&Wpb[(size_t)(n0 + i * 64 + srow) * 2048 + k0 + scol],
                    &Bs[i * 2048 + tid * 8]);
        __syncthreads();
        s16x8 af, bf[4];
        af = *(const s16x8*)&As[(wr * 16 + li) * 32 + lg * 8];
        #pragma unroll
        for (int ni = 0; ni < 4; ++ni)
            bf[ni] = *(const s16x8*)&Bs[(wc * 64 + ni * 16 + li) * 32 + lg * 8];
        #pragma unroll
        for (int ni = 0; ni < 4; ++ni)
            acc[ni] = __builtin_amdgcn_mfma_f32_16x16x32_bf16(af, bf[ni], acc[ni], 0, 0, 0);
    }

    #pragma unroll
    for (int ni = 0; ni < 4; ++ni) {
        int n = n0 + wc * 64 + ni * 16 + li;
        #pragma unroll
        for (int r = 0; r < 4; ++r) {
            int m = m0 + wr * 16 + lg * 4 + r;
            out[(size_t)m * 256 + n] = acc[ni][r];
        }
    }
}

extern "C" void kernel_launch(void* const* d_in, const int* in_sizes, int n_in,
                              void* d_out, int out_size, void* d_ws, size_t ws_size,
                              hipStream_t stream) {
    const float* x  = (const float*)d_in[0];
    const float* Wq = (const float*)d_in[1];
    const float* Wk = (const float*)d_in[2];
    const float* Wv = (const float*)d_in[3];
    const float* bq = (const float*)d_in[4];
    const float* bk = (const float*)d_in[5];
    const float* bv = (const float*)d_in[6];
    const float* Wp = (const float*)d_in[7];
    float* out = (float*)d_out;

    u16* xb   = (u16*)d_ws;               // 2,097,152
    u16* Wqb  = xb   + (1u << 21);        // 524,288 each
    u16* Wkb  = Wqb  + (1u << 19);
    u16* Wvb  = Wkb  + (1u << 19);
    u16* Wpb  = Wvb  + (1u << 19);
    u16* Qb   = Wpb  + (1u << 19);        // 16,777,216
    u16* Kimg = Qb   + (1u << 24);        // 16,777,216
    u16* Vimg = Kimg + (1u << 24);        // 20,971,520 (padded V)
    u16* Ob   = Vimg + 20971520u;         // 16,777,216

    castall<<<4096, 256, 0, stream>>>(x, Wq, Wk, Wv, Wp, xb, Wqb, Wkb, Wvb, Wpb);
    qkv_gemm<<<dim3(64, 48), 256, 0, stream>>>(xb, Wqb, Wkb, Wvb, bq, bk, bv, Qb, Kimg, Vimg);
    attn<<<256, 512, 0, stream>>>(Qb, Kimg, Vimg, Ob);
    out_gemm<<<dim3(256, 2), 256, 0, stream>>>(Ob, Wpb, out);
}

// Round 5
// 156.258 us; speedup vs baseline: 7.5013x; 1.4514x over previous
//
#include <hip/hip_runtime.h>

typedef unsigned short u16;
typedef __attribute__((ext_vector_type(4)))  float f32x4;
typedef __attribute__((ext_vector_type(16))) float f32x16;
typedef __attribute__((ext_vector_type(8)))  short s16x8;   // 8 bf16 MFMA fragment
typedef __attribute__((ext_vector_type(4)))  unsigned short u16x4;

typedef const __attribute__((address_space(1))) void* gp1;
typedef __attribute__((address_space(3))) void* lp3;
#define GLOAD16(g, l) __builtin_amdgcn_global_load_lds((gp1)(g), (lp3)(l), 16, 0, 0)

__device__ __forceinline__ u16 f2bf(float f) {
    union { float f; unsigned u; } c; c.f = f;
    unsigned r = c.u + 0x7fffu + ((c.u >> 16) & 1u);   // RNE
    return (u16)(r >> 16);
}

// ---------------- fp32 -> bf16 cast (all 5 arrays, one launch) ----------------
__global__ void castall(const float* __restrict__ x,  const float* __restrict__ wq,
                        const float* __restrict__ wk, const float* __restrict__ wv,
                        const float* __restrict__ wp,
                        u16* __restrict__ xb,  u16* __restrict__ wqb, u16* __restrict__ wkb,
                        u16* __restrict__ wvb, u16* __restrict__ wpb) {
    int blk = blockIdx.x;
    const float* src; u16* dst; long off;
    if (blk < 2048) { src = x; dst = xb; off = (long)blk * 1024; }
    else {
        int w = (blk - 2048) >> 9, bb = (blk - 2048) & 511;
        src = (w == 0 ? wq : w == 1 ? wk : w == 2 ? wv : wp);
        dst = (w == 0 ? wqb : w == 1 ? wkb : w == 2 ? wvb : wpb);
        off = (long)bb * 1024;
    }
    long i = off + threadIdx.x * 4;
    f32x4 v = *(const f32x4*)(src + i);
    u16x4 o;
    o[0] = f2bf(v[0]); o[1] = f2bf(v[1]); o[2] = f2bf(v[2]); o[3] = f2bf(v[3]);
    *(u16x4*)(dst + i) = o;
}

// ---------------- QKV projection GEMM ----------------
// M=8192 (b*1024+s), N=6144 (w*2048 + h*256 + e), K=256.
// Q -> [B,H,S,256] linear bf16.
// K -> swizzled tile image: per bh, 32 tiles [32 rows(s)][256 cols(e)],
//      elem (r,c) at u16 idx r*256 + ((c&~7)^((r&7)<<3)) + (c&7).
// V -> PADDED tile image: per bh, 32 tiles [256 rows(e)][40 cols(j)], j<32 valid,
//      elem (e,j) at u16 idx e*40 + j. 80B rows -> bank-staggered, no swizzle.
__global__ __launch_bounds__(256) void qkv_gemm(
    const u16* __restrict__ xb,
    const u16* __restrict__ Wqb, const u16* __restrict__ Wkb, const u16* __restrict__ Wvb,
    const float* __restrict__ bq, const float* __restrict__ bk, const float* __restrict__ bv,
    u16* __restrict__ Qb, u16* __restrict__ Kimg, u16* __restrict__ Vimg)
{
    __shared__ u16 As[128 * 32];
    __shared__ u16 Bs[128 * 32];
    const int tid  = threadIdx.x;
    const int lane = tid & 63;
    const int li   = lane & 15, lg = lane >> 4;
    const int wave = tid >> 6;
    const int wr   = wave >> 1, wc = wave & 1;
    const int m0   = blockIdx.x * 128;
    const int n0g  = blockIdx.y * 128;
    const int w    = n0g >> 11;            // 0:Q 1:K 2:V
    const int h    = (n0g >> 8) & 7;
    const int e0   = n0g & 255;            // 0 or 128
    const u16* Wsel = (w == 0 ? Wqb : (w == 1 ? Wkb : Wvb)) + h * 65536;

    const int srow = tid >> 2;             // 0..63
    const int scol = (tid & 3) * 8;

    f32x4 acc[4][4] = {};

    for (int k0 = 0; k0 < 256; k0 += 32) {
        __syncthreads();
        #pragma unroll
        for (int i = 0; i < 2; ++i) {
            int row = i * 64 + srow;
            GLOAD16(&xb[(m0 + row) * 256 + k0 + scol],   &As[i * 2048 + tid * 8]);
            GLOAD16(&Wsel[(e0 + row) * 256 + k0 + scol], &Bs[i * 2048 + tid * 8]);
        }
        __syncthreads();
        s16x8 af[4], bf[4];
        #pragma unroll
        for (int mi = 0; mi < 4; ++mi)
            af[mi] = *(const s16x8*)&As[(wr * 64 + mi * 16 + li) * 32 + lg * 8];
        #pragma unroll
        for (int ni = 0; ni < 4; ++ni)
            bf[ni] = *(const s16x8*)&Bs[(wc * 64 + ni * 16 + li) * 32 + lg * 8];
        #pragma unroll
        for (int mi = 0; mi < 4; ++mi)
            #pragma unroll
            for (int ni = 0; ni < 4; ++ni)
                acc[mi][ni] = __builtin_amdgcn_mfma_f32_16x16x32_bf16(af[mi], bf[ni], acc[mi][ni], 0, 0, 0);
    }

    const int b  = m0 >> 10;
    const int s0 = m0 & 1023;
    if (w == 0) {
        const float* bp = bq + 256 * h;
        #pragma unroll
        for (int ni = 0; ni < 4; ++ni) {
            const int e = e0 + wc * 64 + ni * 16 + li;
            const float bias = bp[e];
            u16* obase = Qb + ((size_t)(b * 8 + h)) * 1024 * 256 + e;
            #pragma unroll
            for (int mi = 0; mi < 4; ++mi)
                #pragma unroll
                for (int r = 0; r < 4; ++r) {
                    int s = s0 + wr * 64 + mi * 16 + lg * 4 + r;
                    obase[(size_t)s * 256] = f2bf(acc[mi][ni][r] + bias);
                }
        }
    } else if (w == 1) {
        const float* bp = bk + 256 * h;
        u16* kb = Kimg + ((size_t)(b * 8 + h)) * 262144;
        #pragma unroll
        for (int ni = 0; ni < 4; ++ni) {
            const int e = e0 + wc * 64 + ni * 16 + li;
            const float bias = bp[e];
            #pragma unroll
            for (int mi = 0; mi < 4; ++mi)
                #pragma unroll
                for (int r = 0; r < 4; ++r) {
                    int s = s0 + wr * 64 + mi * 16 + lg * 4 + r;
                    int t = s >> 5, rr = s & 31;
                    size_t idx = (size_t)t * 8192 + rr * 256
                               + (((e & ~7) ^ ((rr & 7) << 3)) | (e & 7));
                    kb[idx] = f2bf(acc[mi][ni][r] + bias);
                }
        }
    } else {
        const float* bp = bv + 256 * h;
        u16* vb = Vimg + ((size_t)(b * 8 + h)) * 327680;
        #pragma unroll
        for (int ni = 0; ni < 4; ++ni) {
            const int e = e0 + wc * 64 + ni * 16 + li;
            const float bias = bp[e];
            #pragma unroll
            for (int mi = 0; mi < 4; ++mi) {
                int s = s0 + wr * 64 + mi * 16 + lg * 4;   // multiple of 4
                int t = s >> 5, cj = s & 31;
                size_t idx = (size_t)t * 10240 + e * 40 + cj;
                u16x4 pk;
                #pragma unroll
                for (int r = 0; r < 4; ++r) pk[r] = f2bf(acc[mi][ni][r] + bias);
                *(u16x4*)&vb[idx] = pk;
            }
        }
    }
}

// ---------------- flash attention ----------------
// R13: EXACT revert to the R0/session-best structure (83us, proven 3x).
// 256 blocks = 64 (b,h) * 4 q-blocks; 8 waves (512 thr), 1 block/CU (108KB LDS).
// Wave owns 32 q-rows. TRIPLE-buffered K and V; role-split staging (waves 0-3
// stage K: 4 loads/iter, waves 4-7 stage V: 5 loads/iter); counted vmcnt(8)/
// vmcnt(10) at top of iter (2 batches stay in flight -> no drain); raw
// s_barrier (NOT __syncthreads, which force-drains vmcnt).
// Ledger: iter i reads slot i%3 between barrier-A and barrier-B; stage after
// barrier-B targets slot (i+3)%3 == i%3 (just freed). Tile staged at end of
// iter i is consumed at iter i+3: at top of iter j, outstanding = batches
// j+1, j+2 -> vmcnt(2*role_loads) forces batch j resident. Tail: clamped
// re-stage min(i+3,31) keeps the count invariant (extra copies never read).
// ds_read-vs-stage-write hazard closed: compiler's lgkmcnt wait precedes the
// last MFMA, which precedes barrier-B, so all reads complete before any wave's
// post-barrier stage writes.
// (R9 PV-lag reorder: neutral. R10 2-block split: neutral. R12 SM-first +
// single barrier: -84%. This structure is the measured local optimum.)
__device__ __forceinline__ void softmax_pack(
    f32x16& sacc, float& m_run, float& l_run, f32x16* oacc,
    int hi, s16x8& paA, s16x8& paB)
{
    const float C = 0.09016844f;       // log2(e)/sqrt(256)
    const float THR = 16.0f;           // defer-max threshold (raw S units)
    float pm = -1e30f;
    #pragma unroll
    for (int r = 0; r < 16; ++r) pm = fmaxf(pm, sacc[r]);
    pm = fmaxf(pm, __shfl_xor(pm, 32));
    if (!__all(pm - m_run <= THR)) {   // rare
        const float mnew = fmaxf(m_run, pm);
        const float corr = __builtin_amdgcn_exp2f((m_run - mnew) * C);
        l_run *= corr;
        #pragma unroll
        for (int r = 0; r < 16; ++r) {
            float rc = __shfl(corr, (r & 3) + 8 * (r >> 2) + 4 * hi);
            #pragma unroll
            for (int et = 0; et < 8; ++et) oacc[et][r] *= rc;
        }
        m_run = mnew;
    }
    float psum = 0.f;
    #pragma unroll
    for (int r = 0; r < 16; ++r) {
        float p = __builtin_amdgcn_exp2f((sacc[r] - m_run) * C);
        psum += p;
        sacc[r] = p;
    }
    psum += __shfl_xor(psum, 32);
    l_run += psum;
    unsigned dwA[4], dwB[4];
    #pragma unroll
    for (int c = 0; c < 4; ++c) {
        asm("v_cvt_pk_bf16_f32 %0, %1, %2" : "=v"(dwA[c]) : "v"(sacc[4*c]),   "v"(sacc[4*c+1]));
        asm("v_cvt_pk_bf16_f32 %0, %1, %2" : "=v"(dwB[c]) : "v"(sacc[4*c+2]), "v"(sacc[4*c+3]));
    }
    {
        unsigned a0 = dwA[0], a1 = dwA[1], b0 = dwB[0], b1 = dwB[1];
        asm("v_permlane32_swap_b32 %0, %1" : "+v"(a0), "+v"(a1));
        asm("v_permlane32_swap_b32 %0, %1" : "+v"(b0), "+v"(b1));
        union { unsigned u[4]; s16x8 v; } pk;
        pk.u[0] = a0; pk.u[1] = b0; pk.u[2] = a1; pk.u[3] = b1;
        paA = pk.v;
    }
    {
        unsigned a0 = dwA[2], a1 = dwA[3], b0 = dwB[2], b1 = dwB[3];
        asm("v_permlane32_swap_b32 %0, %1" : "+v"(a0), "+v"(a1));
        asm("v_permlane32_swap_b32 %0, %1" : "+v"(b0), "+v"(b1));
        union { unsigned u[4]; s16x8 v; } pk;
        pk.u[0] = a0; pk.u[1] = b0; pk.u[2] = a1; pk.u[3] = b1;
        paB = pk.v;
    }
}

__global__ __launch_bounds__(512, 2) void attn(
    const u16* __restrict__ Qb, const u16* __restrict__ Kimg,
    const u16* __restrict__ Vimg, u16* __restrict__ Ob)
{
    __shared__ u16 kbuf[3][8192];      // [32 j][256 d] swizzled, 16KB each
    __shared__ u16 vbuf[3][10240];     // [256 e][40 j] padded, 20KB each
    const int tid  = threadIdx.x;
    const int lane = tid & 63;
    const int wave = tid >> 6;
    const int col  = lane & 31;        // q-row for S, e-col for O
    const int hi   = lane >> 5;
    const int hi8  = hi * 8;
    const int ksw  = (lane & 7) << 3;  // K-read XOR swizzle
    // XCD swizzle: 256 blocks, 32 per XCD -> 8 distinct (b,h) per XCD
    const int bid  = ((blockIdx.x & 7) << 5) | (blockIdx.x >> 3);
    const int bh   = bid >> 2;
    const int qblk = bid & 3;
    const int q0   = qblk * 256 + wave * 32;   // wave's 32 q-rows

    const u16* qp = Qb + ((size_t)bh * 1024 + q0) * 256;
    const u16* kg = Kimg + (size_t)bh * 262144;
    const u16* vg = Vimg + (size_t)bh * 327680;

    // capture-safe role-split stage: waves 0-3 -> K (4 loads), 4-7 -> V (5 loads)
    #define STAGE(sl, t)                                                          \
        {                                                                         \
            const int sl_ = (sl);                                                 \
            const int t_  = (t);                                                  \
            if (tid < 256) {                                                      \
                const size_t kb_ = (size_t)t_ * 8192 + tid * 8;                   \
                _Pragma("unroll")                                                 \
                for (int c_ = 0; c_ < 4; ++c_)                                    \
                    GLOAD16(&kg[kb_ + c_ * 2048], &kbuf[sl_][c_ * 2048 + tid * 8]); \
            } else {                                                              \
                const int    vt_ = tid - 256;                                     \
                const size_t vb_ = (size_t)t_ * 10240 + vt_ * 8;                  \
                _Pragma("unroll")                                                 \
                for (int c_ = 0; c_ < 5; ++c_)                                    \
                    GLOAD16(&vg[vb_ + c_ * 2048], &vbuf[sl_][c_ * 2048 + vt_ * 8]); \
            }                                                                     \
        }

    // Q B-frags first (their vmcnt retires before the batches we count against)
    s16x8 qf[16];
    #pragma unroll
    for (int dk = 0; dk < 16; ++dk)
        qf[dk] = *(const s16x8*)&qp[(size_t)col * 256 + dk * 16 + hi8];

    // prologue: 3 batches in flight
    STAGE(0, 0);
    STAGE(1, 1);
    STAGE(2, 2);

    f32x16 oacc[8] = {};               // O[q=crow(r,hi)][e=et*32+col]
    float m_run = -1e30f, l_run = 0.f;
    f32x16 sacc;
    s16x8 paA, paB;

    for (int i = 0; i < 32; ++i) {
        // counted wait: allow 2 newest batches in flight -> batch i resident
        if (tid < 256) { asm volatile("s_waitcnt vmcnt(8)"  ::: "memory"); }
        else           { asm volatile("s_waitcnt vmcnt(10)" ::: "memory"); }
        __builtin_amdgcn_s_barrier();              // barrier-A: whole tile i visible
        asm volatile("" ::: "memory");
        const int slot = i % 3;
        const u16* kt = kbuf[slot];
        const u16* vt = vbuf[slot];

        __builtin_amdgcn_s_setprio(1);
        {   // QK: S[j=crow(r,hi)][q=col]
            sacc = (f32x16){};
            const int rb_ = col * 256;
            #pragma unroll
            for (int dk_ = 0; dk_ < 16; ++dk_) {
                s16x8 kf = *(const s16x8*)&kt[rb_ + ((dk_ * 16 + hi8) ^ ksw)];
                sacc = __builtin_amdgcn_mfma_f32_32x32x16_bf16(kf, qf[dk_], sacc, 0, 0, 0);
            }
        }
        __builtin_amdgcn_s_setprio(0);

        softmax_pack(sacc, m_run, l_run, oacc, hi, paA, paB);

        __builtin_amdgcn_s_setprio(1);
        {   // PV
            #pragma unroll
            for (int et_ = 0; et_ < 8; ++et_) {
                s16x8 vf = *(const s16x8*)&vt[(et_ * 32 + col) * 40 + hi8];
                oacc[et_] = __builtin_amdgcn_mfma_f32_32x32x16_bf16(paA, vf, oacc[et_], 0, 0, 0);
            }
            #pragma unroll
            for (int et_ = 0; et_ < 8; ++et_) {
                s16x8 vf = *(const s16x8*)&vt[(et_ * 32 + col) * 40 + 16 + hi8];
                oacc[et_] = __builtin_amdgcn_mfma_f32_32x32x16_bf16(paB, vf, oacc[et_], 0, 0, 0);
            }
        }
        __builtin_amdgcn_s_setprio(0);

        asm volatile("" ::: "memory");
        __builtin_amdgcn_s_barrier();              // barrier-B: slot reads done
        asm volatile("" ::: "memory");
        const int nt = (i + 3 < 32) ? (i + 3) : 31;   // clamp keeps count invariant
        STAGE(slot, nt);                           // slot (i+3)%3 == i%3, just freed
    }
    #undef STAGE

    // normalize + store: Ob [B,S,H*256]
    const float linv = 1.0f / l_run;
    const int b = bh >> 3, h = bh & 7;
    u16* op = Ob + ((size_t)b * 1024) * 2048 + h * 256;
    #pragma unroll
    for (int r = 0; r < 16; ++r) {
        const int crow = (r & 3) + 8 * (r >> 2) + 4 * hi;
        float lr = __shfl(linv, crow);
        const size_t row = q0 + crow;
        #pragma unroll
        for (int et = 0; et < 8; ++et)
            op[row * 2048 + et * 32 + col] = f2bf(oacc[et][r] * lr);
    }
}

// ---------------- output projection ----------------
// out[m, n] = sum_k Ob[m, k] * Wp[n, k]; M=8192, N=256, K=2048; fp32 out.
// R13: BK 32 -> 128. Was 64 k-iters x 2 full-drain barriers for only 4
// MFMAs/wave/iter (barrier-dominated). Now 16 iters x 16 MFMAs/wave/iter.
// LDS 40KB (As 8KB + Bs 32KB), grid (256,2)=512 -> 2 blocks/CU.
// [row][128] bf16 rows are a 16-way bank conflict on ds_read_b128, so the
// k-chunk index is XOR-swizzled with (row&7) BOTH sides (rule #21): LDS dest
// stays linear, the global SOURCE address is inverse-swizzled at staging, and
// fragment reads apply the same XOR. Per-32k-subtile fragment semantics are
// identical to the verified BK=32 version.
__global__ __launch_bounds__(256) void out_gemm(
    const u16* __restrict__ Ob, const u16* __restrict__ Wpb, float* __restrict__ out)
{
    __shared__ u16 As[32 * 128];    // [32 m][16 chunks of 8 u16], chunk^row&7
    __shared__ u16 Bs[128 * 128];   // [128 n][16 chunks], chunk^row&7
    const int tid  = threadIdx.x;
    const int lane = tid & 63;
    const int li   = lane & 15, lg = lane >> 4;
    const int wave = tid >> 6;
    const int wr   = wave >> 1, wc = wave & 1;   // wave tile 16x64
    const int m0   = blockIdx.x * 32;
    const int n0   = blockIdx.y * 128;

    f32x4 acc[4] = {};

    for (int k0 = 0; k0 < 2048; k0 += 128) {
        __syncthreads();
        // stage A: 512 16B-chunks, 2 passes (source pre-swizzled, LDS linear)
        #pragma unroll
        for (int p = 0; p < 2; ++p) {
            const int g = p * 256 + tid, row = g >> 4, cl = g & 15;
            GLOAD16(&Ob[(size_t)(m0 + row) * 2048 + k0 + ((cl ^ (row & 7)) * 8)],
                    &As[g * 8]);
        }
        // stage B: 2048 chunks, 8 passes
        #pragma unroll
        for (int p = 0; p < 8; ++p) {
            const int g = p * 256 + tid, row = g >> 4, cl = g & 15;
            GLOAD16(&Wpb[(size_t)(n0 + row) * 2048 + k0 + ((cl ^ (row & 7)) * 8)],
                    &Bs[g * 8]);
        }
        __syncthreads();

        const int arow = wr * 16 + li;
        s16x8 af[4];
        #pragma unroll
        for (int kk = 0; kk < 4; ++kk)
            af[kk] = *(const s16x8*)&As[arow * 128 + (((kk * 4 + lg) ^ (arow & 7)) * 8)];
        #pragma unroll
        for (int ni = 0; ni < 4; ++ni) {
            const int brow = wc * 64 + ni * 16 + li;
            #pragma unroll
            for (int kk = 0; kk < 4; ++kk) {
                s16x8 bf = *(const s16x8*)&Bs[brow * 128 + (((kk * 4 + lg) ^ (brow & 7)) * 8)];
                acc[ni] = __builtin_amdgcn_mfma_f32_16x16x32_bf16(af[kk], bf, acc[ni], 0, 0, 0);
            }
        }
    }

    #pragma unroll
    for (int ni = 0; ni < 4; ++ni) {
        int n = n0 + wc * 64 + ni * 16 + li;
        #pragma unroll
        for (int r = 0; r < 4; ++r) {
            int m = m0 + wr * 16 + lg * 4 + r;
            out[(size_t)m * 256 + n] = acc[ni][r];
        }
    }
}

extern "C" void kernel_launch(void* const* d_in, const int* in_sizes, int n_in,
                              void* d_out, int out_size, void* d_ws, size_t ws_size,
                              hipStream_t stream) {
    const float* x  = (const float*)d_in[0];
    const float* Wq = (const float*)d_in[1];
    const float* Wk = (const float*)d_in[2];
    const float* Wv = (const float*)d_in[3];
    const float* bq = (const float*)d_in[4];
    const float* bk = (const float*)d_in[5];
    const float* bv = (const float*)d_in[6];
    const float* Wp = (const float*)d_in[7];
    float* out = (float*)d_out;

    u16* xb   = (u16*)d_ws;               // 2,097,152
    u16* Wqb  = xb   + (1u << 21);        // 524,288 each
    u16* Wkb  = Wqb  + (1u << 19);
    u16* Wvb  = Wkb  + (1u << 19);
    u16* Wpb  = Wvb  + (1u << 19);
    u16* Qb   = Wpb  + (1u << 19);        // 16,777,216
    u16* Kimg = Qb   + (1u << 24);        // 16,777,216
    u16* Vimg = Kimg + (1u << 24);        // 20,971,520 (padded V)
    u16* Ob   = Vimg + 20971520u;         // 16,777,216

    castall<<<4096, 256, 0, stream>>>(x, Wq, Wk, Wv, Wp, xb, Wqb, Wkb, Wvb, Wpb);
    qkv_gemm<<<dim3(64, 48), 256, 0, stream>>>(xb, Wqb, Wkb, Wvb, bq, bk, bv, Qb, Kimg, Vimg);
    attn<<<256, 512, 0, stream>>>(Qb, Kimg, Vimg, Ob);
    out_gemm<<<dim3(256, 2), 256, 0, stream>>>(Ob, Wpb, out);
}

// Round 6
// 155.556 us; speedup vs baseline: 7.5351x; 1.0045x over previous
//
#include <hip/hip_runtime.h>

typedef unsigned short u16;
typedef __attribute__((ext_vector_type(4)))  float f32x4;
typedef __attribute__((ext_vector_type(16))) float f32x16;
typedef __attribute__((ext_vector_type(8)))  short s16x8;   // 8 bf16 MFMA fragment
typedef __attribute__((ext_vector_type(4)))  unsigned short u16x4;

typedef const __attribute__((address_space(1))) void* gp1;
typedef __attribute__((address_space(3))) void* lp3;
#define GLOAD16(g, l) __builtin_amdgcn_global_load_lds((gp1)(g), (lp3)(l), 16, 0, 0)

__device__ __forceinline__ u16 f2bf(float f) {
    union { float f; unsigned u; } c; c.f = f;
    unsigned r = c.u + 0x7fffu + ((c.u >> 16) & 1u);   // RNE
    return (u16)(r >> 16);
}

// ---------------- fp32 -> bf16 cast (all 5 arrays, one launch) ----------------
__global__ void castall(const float* __restrict__ x,  const float* __restrict__ wq,
                        const float* __restrict__ wk, const float* __restrict__ wv,
                        const float* __restrict__ wp,
                        u16* __restrict__ xb,  u16* __restrict__ wqb, u16* __restrict__ wkb,
                        u16* __restrict__ wvb, u16* __restrict__ wpb) {
    int blk = blockIdx.x;
    const float* src; u16* dst; long off;
    if (blk < 2048) { src = x; dst = xb; off = (long)blk * 1024; }
    else {
        int w = (blk - 2048) >> 9, bb = (blk - 2048) & 511;
        src = (w == 0 ? wq : w == 1 ? wk : w == 2 ? wv : wp);
        dst = (w == 0 ? wqb : w == 1 ? wkb : w == 2 ? wvb : wpb);
        off = (long)bb * 1024;
    }
    long i = off + threadIdx.x * 4;
    f32x4 v = *(const f32x4*)(src + i);
    u16x4 o;
    o[0] = f2bf(v[0]); o[1] = f2bf(v[1]); o[2] = f2bf(v[2]); o[3] = f2bf(v[3]);
    *(u16x4*)(dst + i) = o;
}

// ---------------- QKV projection GEMM ----------------
// M=8192 (b*1024+s), N=6144 (w*2048 + h*256 + e), K=256.
// R14: BK 32 -> 128 (same disease/cure as out_gemm R13). Was 8 k-iters x 2
// full-drain barriers for 16 MFMAs/wave/iter; now 2 iters x 64 MFMAs/wave/iter.
// LDS 64KB (As 32KB + Bs 32KB) -> 2 blocks/CU at grid 3072.
// [row][128] bf16 tiles use the verified both-sides chunk-XOR swizzle
// (cl ^ (row&7)): inverse-swizzled global SOURCE, linear LDS dest (GLOAD16
// requirement), swizzled ds_read_b128 on the fragment reads.
// Per-32k-subtile fragment semantics identical to the verified BK=32 version.
// Outputs unchanged:
// Q -> [B,H,S,256] linear bf16.
// K -> swizzled tile image: per bh, 32 tiles [32 rows(s)][256 cols(e)],
//      elem (r,c) at u16 idx r*256 + ((c&~7)^((r&7)<<3)) + (c&7).
// V -> PADDED tile image: per bh, 32 tiles [256 rows(e)][40 cols(j)], j<32 valid,
//      elem (e,j) at u16 idx e*40 + j. 80B rows -> bank-staggered, no swizzle.
__global__ __launch_bounds__(256) void qkv_gemm(
    const u16* __restrict__ xb,
    const u16* __restrict__ Wqb, const u16* __restrict__ Wkb, const u16* __restrict__ Wvb,
    const float* __restrict__ bq, const float* __restrict__ bk, const float* __restrict__ bv,
    u16* __restrict__ Qb, u16* __restrict__ Kimg, u16* __restrict__ Vimg)
{
    __shared__ u16 As[128 * 128];   // [128 m][16 chunks of 8 u16], chunk^row&7
    __shared__ u16 Bs[128 * 128];   // [128 n][16 chunks], chunk^row&7
    const int tid  = threadIdx.x;
    const int lane = tid & 63;
    const int li   = lane & 15, lg = lane >> 4;
    const int wave = tid >> 6;
    const int wr   = wave >> 1, wc = wave & 1;
    const int m0   = blockIdx.x * 128;
    const int n0g  = blockIdx.y * 128;
    const int w    = n0g >> 11;            // 0:Q 1:K 2:V
    const int h    = (n0g >> 8) & 7;
    const int e0   = n0g & 255;            // 0 or 128
    const u16* Wsel = (w == 0 ? Wqb : (w == 1 ? Wkb : Wvb)) + h * 65536;

    f32x4 acc[4][4] = {};

    for (int k0 = 0; k0 < 256; k0 += 128) {
        __syncthreads();
        // stage A + B: 2048 16B-chunks each, 8 passes each
        #pragma unroll
        for (int p = 0; p < 8; ++p) {
            const int g = p * 256 + tid, row = g >> 4, cl = g & 15;
            const size_t soff = ((size_t)row) * 256 + k0 + ((cl ^ (row & 7)) * 8);
            GLOAD16(&xb[(size_t)m0 * 256 + soff],   &As[g * 8]);
            GLOAD16(&Wsel[(size_t)e0 * 256 + soff], &Bs[g * 8]);
        }
        __syncthreads();

        #pragma unroll
        for (int kk = 0; kk < 4; ++kk) {
            s16x8 af[4], bf[4];
            #pragma unroll
            for (int mi = 0; mi < 4; ++mi) {
                const int arow = wr * 64 + mi * 16 + li;
                af[mi] = *(const s16x8*)&As[arow * 128 + (((kk * 4 + lg) ^ (arow & 7)) * 8)];
            }
            #pragma unroll
            for (int ni = 0; ni < 4; ++ni) {
                const int brow = wc * 64 + ni * 16 + li;
                bf[ni] = *(const s16x8*)&Bs[brow * 128 + (((kk * 4 + lg) ^ (brow & 7)) * 8)];
            }
            #pragma unroll
            for (int mi = 0; mi < 4; ++mi)
                #pragma unroll
                for (int ni = 0; ni < 4; ++ni)
                    acc[mi][ni] = __builtin_amdgcn_mfma_f32_16x16x32_bf16(af[mi], bf[ni], acc[mi][ni], 0, 0, 0);
        }
    }

    const int b  = m0 >> 10;
    const int s0 = m0 & 1023;
    if (w == 0) {
        const float* bp = bq + 256 * h;
        #pragma unroll
        for (int ni = 0; ni < 4; ++ni) {
            const int e = e0 + wc * 64 + ni * 16 + li;
            const float bias = bp[e];
            u16* obase = Qb + ((size_t)(b * 8 + h)) * 1024 * 256 + e;
            #pragma unroll
            for (int mi = 0; mi < 4; ++mi)
                #pragma unroll
                for (int r = 0; r < 4; ++r) {
                    int s = s0 + wr * 64 + mi * 16 + lg * 4 + r;
                    obase[(size_t)s * 256] = f2bf(acc[mi][ni][r] + bias);
                }
        }
    } else if (w == 1) {
        const float* bp = bk + 256 * h;
        u16* kb = Kimg + ((size_t)(b * 8 + h)) * 262144;
        #pragma unroll
        for (int ni = 0; ni < 4; ++ni) {
            const int e = e0 + wc * 64 + ni * 16 + li;
            const float bias = bp[e];
            #pragma unroll
            for (int mi = 0; mi < 4; ++mi)
                #pragma unroll
                for (int r = 0; r < 4; ++r) {
                    int s = s0 + wr * 64 + mi * 16 + lg * 4 + r;
                    int t = s >> 5, rr = s & 31;
                    size_t idx = (size_t)t * 8192 + rr * 256
                               + (((e & ~7) ^ ((rr & 7) << 3)) | (e & 7));
                    kb[idx] = f2bf(acc[mi][ni][r] + bias);
                }
        }
    } else {
        const float* bp = bv + 256 * h;
        u16* vb = Vimg + ((size_t)(b * 8 + h)) * 327680;
        #pragma unroll
        for (int ni = 0; ni < 4; ++ni) {
            const int e = e0 + wc * 64 + ni * 16 + li;
            const float bias = bp[e];
            #pragma unroll
            for (int mi = 0; mi < 4; ++mi) {
                int s = s0 + wr * 64 + mi * 16 + lg * 4;   // multiple of 4
                int t = s >> 5, cj = s & 31;
                size_t idx = (size_t)t * 10240 + e * 40 + cj;
                u16x4 pk;
                #pragma unroll
                for (int r = 0; r < 4; ++r) pk[r] = f2bf(acc[mi][ni][r] + bias);
                *(u16x4*)&vb[idx] = pk;
            }
        }
    }
}

// ---------------- flash attention ----------------
// R0/session-best structure (83us, proven 4x).
// 256 blocks = 64 (b,h) * 4 q-blocks; 8 waves (512 thr), 1 block/CU (108KB LDS).
// Wave owns 32 q-rows. TRIPLE-buffered K and V; role-split staging (waves 0-3
// stage K: 4 loads/iter, waves 4-7 stage V: 5 loads/iter); counted vmcnt(8)/
// vmcnt(10) at top of iter (2 batches stay in flight -> no drain); raw
// s_barrier (NOT __syncthreads, which force-drains vmcnt).
// Ledger: iter i reads slot i%3 between barrier-A and barrier-B; stage after
// barrier-B targets slot (i+3)%3 == i%3 (just freed). Tile staged at end of
// iter i is consumed at iter i+3: at top of iter j, outstanding = batches
// j+1, j+2 -> vmcnt(2*role_loads) forces batch j resident. Tail: clamped
// re-stage min(i+3,31) keeps the count invariant (extra copies never read).
// ds_read-vs-stage-write hazard closed: compiler's lgkmcnt wait precedes the
// last MFMA, which precedes barrier-B, so all reads complete before any wave's
// post-barrier stage writes.
// (R9 PV-lag reorder: neutral. R10 2-block split: neutral. R12 SM-first +
// single barrier: -84%. This structure is the measured local optimum.)
__device__ __forceinline__ void softmax_pack(
    f32x16& sacc, float& m_run, float& l_run, f32x16* oacc,
    int hi, s16x8& paA, s16x8& paB)
{
    const float C = 0.09016844f;       // log2(e)/sqrt(256)
    const float THR = 16.0f;           // defer-max threshold (raw S units)
    float pm = -1e30f;
    #pragma unroll
    for (int r = 0; r < 16; ++r) pm = fmaxf(pm, sacc[r]);
    pm = fmaxf(pm, __shfl_xor(pm, 32));
    if (!__all(pm - m_run <= THR)) {   // rare
        const float mnew = fmaxf(m_run, pm);
        const float corr = __builtin_amdgcn_exp2f((m_run - mnew) * C);
        l_run *= corr;
        #pragma unroll
        for (int r = 0; r < 16; ++r) {
            float rc = __shfl(corr, (r & 3) + 8 * (r >> 2) + 4 * hi);
            #pragma unroll
            for (int et = 0; et < 8; ++et) oacc[et][r] *= rc;
        }
        m_run = mnew;
    }
    float psum = 0.f;
    #pragma unroll
    for (int r = 0; r < 16; ++r) {
        float p = __builtin_amdgcn_exp2f((sacc[r] - m_run) * C);
        psum += p;
        sacc[r] = p;
    }
    psum += __shfl_xor(psum, 32);
    l_run += psum;
    unsigned dwA[4], dwB[4];
    #pragma unroll
    for (int c = 0; c < 4; ++c) {
        asm("v_cvt_pk_bf16_f32 %0, %1, %2" : "=v"(dwA[c]) : "v"(sacc[4*c]),   "v"(sacc[4*c+1]));
        asm("v_cvt_pk_bf16_f32 %0, %1, %2" : "=v"(dwB[c]) : "v"(sacc[4*c+2]), "v"(sacc[4*c+3]));
    }
    {
        unsigned a0 = dwA[0], a1 = dwA[1], b0 = dwB[0], b1 = dwB[1];
        asm("v_permlane32_swap_b32 %0, %1" : "+v"(a0), "+v"(a1));
        asm("v_permlane32_swap_b32 %0, %1" : "+v"(b0), "+v"(b1));
        union { unsigned u[4]; s16x8 v; } pk;
        pk.u[0] = a0; pk.u[1] = b0; pk.u[2] = a1; pk.u[3] = b1;
        paA = pk.v;
    }
    {
        unsigned a0 = dwA[2], a1 = dwA[3], b0 = dwB[2], b1 = dwB[3];
        asm("v_permlane32_swap_b32 %0, %1" : "+v"(a0), "+v"(a1));
        asm("v_permlane32_swap_b32 %0, %1" : "+v"(b0), "+v"(b1));
        union { unsigned u[4]; s16x8 v; } pk;
        pk.u[0] = a0; pk.u[1] = b0; pk.u[2] = a1; pk.u[3] = b1;
        paB = pk.v;
    }
}

__global__ __launch_bounds__(512, 2) void attn(
    const u16* __restrict__ Qb, const u16* __restrict__ Kimg,
    const u16* __restrict__ Vimg, u16* __restrict__ Ob)
{
    __shared__ u16 kbuf[3][8192];      // [32 j][256 d] swizzled, 16KB each
    __shared__ u16 vbuf[3][10240];     // [256 e][40 j] padded, 20KB each
    const int tid  = threadIdx.x;
    const int lane = tid & 63;
    const int wave = tid >> 6;
    const int col  = lane & 31;        // q-row for S, e-col for O
    const int hi   = lane >> 5;
    const int hi8  = hi * 8;
    const int ksw  = (lane & 7) << 3;  // K-read XOR swizzle
    // XCD swizzle: 256 blocks, 32 per XCD -> 8 distinct (b,h) per XCD
    const int bid  = ((blockIdx.x & 7) << 5) | (blockIdx.x >> 3);
    const int bh   = bid >> 2;
    const int qblk = bid & 3;
    const int q0   = qblk * 256 + wave * 32;   // wave's 32 q-rows

    const u16* qp = Qb + ((size_t)bh * 1024 + q0) * 256;
    const u16* kg = Kimg + (size_t)bh * 262144;
    const u16* vg = Vimg + (size_t)bh * 327680;

    // capture-safe role-split stage: waves 0-3 -> K (4 loads), 4-7 -> V (5 loads)
    #define STAGE(sl, t)                                                          \
        {                                                                         \
            const int sl_ = (sl);                                                 \
            const int t_  = (t);                                                  \
            if (tid < 256) {                                                      \
                const size_t kb_ = (size_t)t_ * 8192 + tid * 8;                   \
                _Pragma("unroll")                                                 \
                for (int c_ = 0; c_ < 4; ++c_)                                    \
                    GLOAD16(&kg[kb_ + c_ * 2048], &kbuf[sl_][c_ * 2048 + tid * 8]); \
            } else {                                                              \
                const int    vt_ = tid - 256;                                     \
                const size_t vb_ = (size_t)t_ * 10240 + vt_ * 8;                  \
                _Pragma("unroll")                                                 \
                for (int c_ = 0; c_ < 5; ++c_)                                    \
                    GLOAD16(&vg[vb_ + c_ * 2048], &vbuf[sl_][c_ * 2048 + vt_ * 8]); \
            }                                                                     \
        }

    // Q B-frags first (their vmcnt retires before the batches we count against)
    s16x8 qf[16];
    #pragma unroll
    for (int dk = 0; dk < 16; ++dk)
        qf[dk] = *(const s16x8*)&qp[(size_t)col * 256 + dk * 16 + hi8];

    // prologue: 3 batches in flight
    STAGE(0, 0);
    STAGE(1, 1);
    STAGE(2, 2);

    f32x16 oacc[8] = {};               // O[q=crow(r,hi)][e=et*32+col]
    float m_run = -1e30f, l_run = 0.f;
    f32x16 sacc;
    s16x8 paA, paB;

    for (int i = 0; i < 32; ++i) {
        // counted wait: allow 2 newest batches in flight -> batch i resident
        if (tid < 256) { asm volatile("s_waitcnt vmcnt(8)"  ::: "memory"); }
        else           { asm volatile("s_waitcnt vmcnt(10)" ::: "memory"); }
        __builtin_amdgcn_s_barrier();              // barrier-A: whole tile i visible
        asm volatile("" ::: "memory");
        const int slot = i % 3;
        const u16* kt = kbuf[slot];
        const u16* vt = vbuf[slot];

        __builtin_amdgcn_s_setprio(1);
        {   // QK: S[j=crow(r,hi)][q=col]
            sacc = (f32x16){};
            const int rb_ = col * 256;
            #pragma unroll
            for (int dk_ = 0; dk_ < 16; ++dk_) {
                s16x8 kf = *(const s16x8*)&kt[rb_ + ((dk_ * 16 + hi8) ^ ksw)];
                sacc = __builtin_amdgcn_mfma_f32_32x32x16_bf16(kf, qf[dk_], sacc, 0, 0, 0);
            }
        }
        __builtin_amdgcn_s_setprio(0);

        softmax_pack(sacc, m_run, l_run, oacc, hi, paA, paB);

        __builtin_amdgcn_s_setprio(1);
        {   // PV
            #pragma unroll
            for (int et_ = 0; et_ < 8; ++et_) {
                s16x8 vf = *(const s16x8*)&vt[(et_ * 32 + col) * 40 + hi8];
                oacc[et_] = __builtin_amdgcn_mfma_f32_32x32x16_bf16(paA, vf, oacc[et_], 0, 0, 0);
            }
            #pragma unroll
            for (int et_ = 0; et_ < 8; ++et_) {
                s16x8 vf = *(const s16x8*)&vt[(et_ * 32 + col) * 40 + 16 + hi8];
                oacc[et_] = __builtin_amdgcn_mfma_f32_32x32x16_bf16(paB, vf, oacc[et_], 0, 0, 0);
            }
        }
        __builtin_amdgcn_s_setprio(0);

        asm volatile("" ::: "memory");
        __builtin_amdgcn_s_barrier();              // barrier-B: slot reads done
        asm volatile("" ::: "memory");
        const int nt = (i + 3 < 32) ? (i + 3) : 31;   // clamp keeps count invariant
        STAGE(slot, nt);                           // slot (i+3)%3 == i%3, just freed
    }
    #undef STAGE

    // normalize + store: Ob [B,S,H*256]
    const float linv = 1.0f / l_run;
    const int b = bh >> 3, h = bh & 7;
    u16* op = Ob + ((size_t)b * 1024) * 2048 + h * 256;
    #pragma unroll
    for (int r = 0; r < 16; ++r) {
        const int crow = (r & 3) + 8 * (r >> 2) + 4 * hi;
        float lr = __shfl(linv, crow);
        const size_t row = q0 + crow;
        #pragma unroll
        for (int et = 0; et < 8; ++et)
            op[row * 2048 + et * 32 + col] = f2bf(oacc[et][r] * lr);
    }
}

// ---------------- output projection ----------------
// out[m, n] = sum_k Ob[m, k] * Wp[n, k]; M=8192, N=256, K=2048; fp32 out.
// R13 (validated, -11us): BK=128, 16 iters x 16 MFMAs/wave/iter, 40KB LDS,
// both-sides chunk-XOR swizzle (cl ^ (row&7)).
__global__ __launch_bounds__(256) void out_gemm(
    const u16* __restrict__ Ob, const u16* __restrict__ Wpb, float* __restrict__ out)
{
    __shared__ u16 As[32 * 128];    // [32 m][16 chunks of 8 u16], chunk^row&7
    __shared__ u16 Bs[128 * 128];   // [128 n][16 chunks], chunk^row&7
    const int tid  = threadIdx.x;
    const int lane = tid & 63;
    const int li   = lane & 15, lg = lane >> 4;
    const int wave = tid >> 6;
    const int wr   = wave >> 1, wc = wave & 1;   // wave tile 16x64
    const int m0   = blockIdx.x * 32;
    const int n0   = blockIdx.y * 128;

    f32x4 acc[4] = {};

    for (int k0 = 0; k0 < 2048; k0 += 128) {
        __syncthreads();
        // stage A: 512 16B-chunks, 2 passes (source pre-swizzled, LDS linear)
        #pragma unroll
        for (int p = 0; p < 2; ++p) {
            const int g = p * 256 + tid, row = g >> 4, cl = g & 15;
            GLOAD16(&Ob[(size_t)(m0 + row) * 2048 + k0 + ((cl ^ (row & 7)) * 8)],
                    &As[g * 8]);
        }
        // stage B: 2048 chunks, 8 passes
        #pragma unroll
        for (int p = 0; p < 8; ++p) {
            const int g = p * 256 + tid, row = g >> 4, cl = g & 15;
            GLOAD16(&Wpb[(size_t)(n0 + row) * 2048 + k0 + ((cl ^ (row & 7)) * 8)],
                    &Bs[g * 8]);
        }
        __syncthreads();

        const int arow = wr * 16 + li;
        s16x8 af[4];
        #pragma unroll
        for (int kk = 0; kk < 4; ++kk)
            af[kk] = *(const s16x8*)&As[arow * 128 + (((kk * 4 + lg) ^ (arow & 7)) * 8)];
        #pragma unroll
        for (int ni = 0; ni < 4; ++ni) {
            const int brow = wc * 64 + ni * 16 + li;
            #pragma unroll
            for (int kk = 0; kk < 4; ++kk) {
                s16x8 bf = *(const s16x8*)&Bs[brow * 128 + (((kk * 4 + lg) ^ (brow & 7)) * 8)];
                acc[ni] = __builtin_amdgcn_mfma_f32_16x16x32_bf16(af[kk], bf, acc[ni], 0, 0, 0);
            }
        }
    }

    #pragma unroll
    for (int ni = 0; ni < 4; ++ni) {
        int n = n0 + wc * 64 + ni * 16 + li;
        #pragma unroll
        for (int r = 0; r < 4; ++r) {
            int m = m0 + wr * 16 + lg * 4 + r;
            out[(size_t)m * 256 + n] = acc[ni][r];
        }
    }
}

extern "C" void kernel_launch(void* const* d_in, const int* in_sizes, int n_in,
                              void* d_out, int out_size, void* d_ws, size_t ws_size,
                              hipStream_t stream) {
    const float* x  = (const float*)d_in[0];
    const float* Wq = (const float*)d_in[1];
    const float* Wk = (const float*)d_in[2];
    const float* Wv = (const float*)d_in[3];
    const float* bq = (const float*)d_in[4];
    const float* bk = (const float*)d_in[5];
    const float* bv = (const float*)d_in[6];
    const float* Wp = (const float*)d_in[7];
    float* out = (float*)d_out;

    u16* xb   = (u16*)d_ws;               // 2,097,152
    u16* Wqb  = xb   + (1u << 21);        // 524,288 each
    u16* Wkb  = Wqb  + (1u << 19);
    u16* Wvb  = Wkb  + (1u << 19);
    u16* Wpb  = Wvb  + (1u << 19);
    u16* Qb   = Wpb  + (1u << 19);        // 16,777,216
    u16* Kimg = Qb   + (1u << 24);        // 16,777,216
    u16* Vimg = Kimg + (1u << 24);        // 20,971,520 (padded V)
    u16* Ob   = Vimg + 20971520u;         // 16,777,216

    castall<<<4096, 256, 0, stream>>>(x, Wq, Wk, Wv, Wp, xb, Wqb, Wkb, Wvb, Wpb);
    qkv_gemm<<<dim3(64, 48), 256, 0, stream>>>(xb, Wqb, Wkb, Wvb, bq, bk, bv, Qb, Kimg, Vimg);
    attn<<<256, 512, 0, stream>>>(Qb, Kimg, Vimg, Ob);
    out_gemm<<<dim3(256, 2), 256, 0, stream>>>(Ob, Wpb, out);
}

// Round 7
// 152.408 us; speedup vs baseline: 7.6907x; 1.0207x over previous
//
#include <hip/hip_runtime.h>

typedef unsigned short u16;
typedef __attribute__((ext_vector_type(4)))  float f32x4;
typedef __attribute__((ext_vector_type(16))) float f32x16;
typedef __attribute__((ext_vector_type(8)))  short s16x8;   // 8 bf16 MFMA fragment
typedef __attribute__((ext_vector_type(4)))  unsigned short u16x4;
typedef __attribute__((ext_vector_type(8)))  unsigned short u16x8;

typedef const __attribute__((address_space(1))) void* gp1;
typedef __attribute__((address_space(3))) void* lp3;
#define GLOAD16(g, l) __builtin_amdgcn_global_load_lds((gp1)(g), (lp3)(l), 16, 0, 0)

__device__ __forceinline__ u16 f2bf(float f) {
    union { float f; unsigned u; } c; c.f = f;
    unsigned r = c.u + 0x7fffu + ((c.u >> 16) & 1u);   // RNE
    return (u16)(r >> 16);
}

// ---------------- fp32 -> bf16 cast (all 5 arrays, one launch) ----------------
__global__ void castall(const float* __restrict__ x,  const float* __restrict__ wq,
                        const float* __restrict__ wk, const float* __restrict__ wv,
                        const float* __restrict__ wp,
                        u16* __restrict__ xb,  u16* __restrict__ wqb, u16* __restrict__ wkb,
                        u16* __restrict__ wvb, u16* __restrict__ wpb) {
    int blk = blockIdx.x;
    const float* src; u16* dst; long off;
    if (blk < 2048) { src = x; dst = xb; off = (long)blk * 1024; }
    else {
        int w = (blk - 2048) >> 9, bb = (blk - 2048) & 511;
        src = (w == 0 ? wq : w == 1 ? wk : w == 2 ? wv : wp);
        dst = (w == 0 ? wqb : w == 1 ? wkb : w == 2 ? wvb : wpb);
        off = (long)bb * 1024;
    }
    long i = off + threadIdx.x * 4;
    f32x4 v = *(const f32x4*)(src + i);
    u16x4 o;
    o[0] = f2bf(v[0]); o[1] = f2bf(v[1]); o[2] = f2bf(v[2]); o[3] = f2bf(v[3]);
    *(u16x4*)(dst + i) = o;
}

// ---------------- QKV projection GEMM ----------------
// M=8192 (b*1024+s), N=6144 (w*2048 + h*256 + e), K=256.
// BK=128 (R14), 2 k-iters x 64 MFMAs/wave/iter, both-sides chunk-XOR swizzle.
// R15: V epilogue rewritten as an LDS transpose bounce. The old path scattered
// u16x4 (8B) stores at stride 80B -> ~64 L2 transactions per store instr over
// 41.9 MB of Vimg (likely the reason R14's k-loop change was neutral: the
// epilogue, not the k-loop, dominates). New path: acc -> LDS Vt[128 e][132 s]
// (8B contiguous per thread, pad 132 spreads banks), barrier, coalesced
// readback rows -> 16B global stores (4 lanes x 16B = 64B segments per 32-j
// row segment). Image bytes identical.
// Outputs unchanged:
// Q -> [B,H,S,256] linear bf16.
// K -> swizzled tile image: per bh, 32 tiles [32 rows(s)][256 cols(e)],
//      elem (r,c) at u16 idx r*256 + ((c&~7)^((r&7)<<3)) + (c&7).
// V -> PADDED tile image: per bh, 32 tiles [256 rows(e)][40 cols(j)], j<32 valid,
//      elem (e,j) at u16 idx e*40 + j. 80B rows -> bank-staggered, no swizzle.
__global__ __launch_bounds__(256) void qkv_gemm(
    const u16* __restrict__ xb,
    const u16* __restrict__ Wqb, const u16* __restrict__ Wkb, const u16* __restrict__ Wvb,
    const float* __restrict__ bq, const float* __restrict__ bk, const float* __restrict__ bv,
    u16* __restrict__ Qb, u16* __restrict__ Kimg, u16* __restrict__ Vimg)
{
    __shared__ u16 smem[32768];     // As [0,16384) | Bs [16384,32768); V bounce reuses
    u16* As = smem;                 // [128 m][16 chunks of 8 u16], chunk^row&7
    u16* Bs = smem + 16384;         // [128 n][16 chunks], chunk^row&7
    const int tid  = threadIdx.x;
    const int lane = tid & 63;
    const int li   = lane & 15, lg = lane >> 4;
    const int wave = tid >> 6;
    const int wr   = wave >> 1, wc = wave & 1;
    const int m0   = blockIdx.x * 128;
    const int n0g  = blockIdx.y * 128;
    const int w    = n0g >> 11;            // 0:Q 1:K 2:V
    const int h    = (n0g >> 8) & 7;
    const int e0   = n0g & 255;            // 0 or 128
    const u16* Wsel = (w == 0 ? Wqb : (w == 1 ? Wkb : Wvb)) + h * 65536;

    f32x4 acc[4][4] = {};

    for (int k0 = 0; k0 < 256; k0 += 128) {
        __syncthreads();
        // stage A + B: 2048 16B-chunks each, 8 passes each
        #pragma unroll
        for (int p = 0; p < 8; ++p) {
            const int g = p * 256 + tid, row = g >> 4, cl = g & 15;
            const size_t soff = ((size_t)row) * 256 + k0 + ((cl ^ (row & 7)) * 8);
            GLOAD16(&xb[(size_t)m0 * 256 + soff],   &As[g * 8]);
            GLOAD16(&Wsel[(size_t)e0 * 256 + soff], &Bs[g * 8]);
        }
        __syncthreads();

        #pragma unroll
        for (int kk = 0; kk < 4; ++kk) {
            s16x8 af[4], bf[4];
            #pragma unroll
            for (int mi = 0; mi < 4; ++mi) {
                const int arow = wr * 64 + mi * 16 + li;
                af[mi] = *(const s16x8*)&As[arow * 128 + (((kk * 4 + lg) ^ (arow & 7)) * 8)];
            }
            #pragma unroll
            for (int ni = 0; ni < 4; ++ni) {
                const int brow = wc * 64 + ni * 16 + li;
                bf[ni] = *(const s16x8*)&Bs[brow * 128 + (((kk * 4 + lg) ^ (brow & 7)) * 8)];
            }
            #pragma unroll
            for (int mi = 0; mi < 4; ++mi)
                #pragma unroll
                for (int ni = 0; ni < 4; ++ni)
                    acc[mi][ni] = __builtin_amdgcn_mfma_f32_16x16x32_bf16(af[mi], bf[ni], acc[mi][ni], 0, 0, 0);
        }
    }

    const int b  = m0 >> 10;
    const int s0 = m0 & 1023;
    if (w == 0) {
        const float* bp = bq + 256 * h;
        #pragma unroll
        for (int ni = 0; ni < 4; ++ni) {
            const int e = e0 + wc * 64 + ni * 16 + li;
            const float bias = bp[e];
            u16* obase = Qb + ((size_t)(b * 8 + h)) * 1024 * 256 + e;
            #pragma unroll
            for (int mi = 0; mi < 4; ++mi)
                #pragma unroll
                for (int r = 0; r < 4; ++r) {
                    int s = s0 + wr * 64 + mi * 16 + lg * 4 + r;
                    obase[(size_t)s * 256] = f2bf(acc[mi][ni][r] + bias);
                }
        }
    } else if (w == 1) {
        const float* bp = bk + 256 * h;
        u16* kb = Kimg + ((size_t)(b * 8 + h)) * 262144;
        #pragma unroll
        for (int ni = 0; ni < 4; ++ni) {
            const int e = e0 + wc * 64 + ni * 16 + li;
            const float bias = bp[e];
            #pragma unroll
            for (int mi = 0; mi < 4; ++mi)
                #pragma unroll
                for (int r = 0; r < 4; ++r) {
                    int s = s0 + wr * 64 + mi * 16 + lg * 4 + r;
                    int t = s >> 5, rr = s & 31;
                    size_t idx = (size_t)t * 8192 + rr * 256
                               + (((e & ~7) ^ ((rr & 7) << 3)) | (e & 7));
                    kb[idx] = f2bf(acc[mi][ni][r] + bias);
                }
        }
    } else {
        // V: LDS transpose bounce. Vt[128 e][132 s] u16 (pad 132 -> bank spread).
        const float* bp = bv + 256 * h;
        u16* vb = Vimg + ((size_t)(b * 8 + h)) * 327680;
        const int t0 = s0 >> 5;            // first of this block's 4 j-tiles
        u16* Vt = smem;                    // 128*132 = 16896 u16 = 33KB <= 64KB
        __syncthreads();                   // As/Bs reads complete
        #pragma unroll
        for (int ni = 0; ni < 4; ++ni) {
            const int eloc = wc * 64 + ni * 16 + li;
            const float bias = bp[e0 + eloc];
            #pragma unroll
            for (int mi = 0; mi < 4; ++mi) {
                const int sloc = wr * 64 + mi * 16 + lg * 4;
                u16x4 pk;
                #pragma unroll
                for (int r = 0; r < 4; ++r) pk[r] = f2bf(acc[mi][ni][r] + bias);
                *(u16x4*)&Vt[eloc * 132 + sloc] = pk;   // 8B contiguous in s
            }
        }
        __syncthreads();
        // readback: 2048 16B-chunks (128 e x 4 tiles x 4 chunks), 8 passes.
        // 4 consecutive tids cover one 64B row-segment (coalesced).
        #pragma unroll
        for (int p = 0; p < 8; ++p) {
            const int g    = p * 256 + tid;
            const int eloc = g >> 4;
            const int tt   = (g >> 2) & 3;
            const int ch   = g & 3;
            const int sloc = tt * 32 + ch * 8;
            u16x8 v = *(const u16x8*)&Vt[eloc * 132 + sloc];
            *(u16x8*)&vb[(size_t)(t0 + tt) * 10240 + (size_t)(e0 + eloc) * 40 + ch * 8] = v;
        }
    }
}

// ---------------- flash attention ----------------
// R0/session-best structure (83us, proven 5x).
// 256 blocks = 64 (b,h) * 4 q-blocks; 8 waves (512 thr), 1 block/CU (108KB LDS).
// Wave owns 32 q-rows. TRIPLE-buffered K and V; role-split staging (waves 0-3
// stage K: 4 loads/iter, waves 4-7 stage V: 5 loads/iter); counted vmcnt(8)/
// vmcnt(10) at top of iter (2 batches stay in flight -> no drain); raw
// s_barrier (NOT __syncthreads, which force-drains vmcnt).
// Ledger: iter i reads slot i%3 between barrier-A and barrier-B; stage after
// barrier-B targets slot (i+3)%3 == i%3 (just freed). Tile staged at end of
// iter i is consumed at iter i+3: at top of iter j, outstanding = batches
// j+1, j+2 -> vmcnt(2*role_loads) forces batch j resident. Tail: clamped
// re-stage min(i+3,31) keeps the count invariant (extra copies never read).
// ds_read-vs-stage-write hazard closed: compiler's lgkmcnt wait precedes the
// last MFMA, which precedes barrier-B, so all reads complete before any wave's
// post-barrier stage writes.
// (R9 PV-lag reorder: neutral. R10 2-block split: neutral. R12 SM-first +
// single barrier: -84%. This structure is the measured local optimum.)
__device__ __forceinline__ void softmax_pack(
    f32x16& sacc, float& m_run, float& l_run, f32x16* oacc,
    int hi, s16x8& paA, s16x8& paB)
{
    const float C = 0.09016844f;       // log2(e)/sqrt(256)
    const float THR = 16.0f;           // defer-max threshold (raw S units)
    float pm = -1e30f;
    #pragma unroll
    for (int r = 0; r < 16; ++r) pm = fmaxf(pm, sacc[r]);
    pm = fmaxf(pm, __shfl_xor(pm, 32));
    if (!__all(pm - m_run <= THR)) {   // rare
        const float mnew = fmaxf(m_run, pm);
        const float corr = __builtin_amdgcn_exp2f((m_run - mnew) * C);
        l_run *= corr;
        #pragma unroll
        for (int r = 0; r < 16; ++r) {
            float rc = __shfl(corr, (r & 3) + 8 * (r >> 2) + 4 * hi);
            #pragma unroll
            for (int et = 0; et < 8; ++et) oacc[et][r] *= rc;
        }
        m_run = mnew;
    }
    float psum = 0.f;
    #pragma unroll
    for (int r = 0; r < 16; ++r) {
        float p = __builtin_amdgcn_exp2f((sacc[r] - m_run) * C);
        psum += p;
        sacc[r] = p;
    }
    psum += __shfl_xor(psum, 32);
    l_run += psum;
    unsigned dwA[4], dwB[4];
    #pragma unroll
    for (int c = 0; c < 4; ++c) {
        asm("v_cvt_pk_bf16_f32 %0, %1, %2" : "=v"(dwA[c]) : "v"(sacc[4*c]),   "v"(sacc[4*c+1]));
        asm("v_cvt_pk_bf16_f32 %0, %1, %2" : "=v"(dwB[c]) : "v"(sacc[4*c+2]), "v"(sacc[4*c+3]));
    }
    {
        unsigned a0 = dwA[0], a1 = dwA[1], b0 = dwB[0], b1 = dwB[1];
        asm("v_permlane32_swap_b32 %0, %1" : "+v"(a0), "+v"(a1));
        asm("v_permlane32_swap_b32 %0, %1" : "+v"(b0), "+v"(b1));
        union { unsigned u[4]; s16x8 v; } pk;
        pk.u[0] = a0; pk.u[1] = b0; pk.u[2] = a1; pk.u[3] = b1;
        paA = pk.v;
    }
    {
        unsigned a0 = dwA[2], a1 = dwA[3], b0 = dwB[2], b1 = dwB[3];
        asm("v_permlane32_swap_b32 %0, %1" : "+v"(a0), "+v"(a1));
        asm("v_permlane32_swap_b32 %0, %1" : "+v"(b0), "+v"(b1));
        union { unsigned u[4]; s16x8 v; } pk;
        pk.u[0] = a0; pk.u[1] = b0; pk.u[2] = a1; pk.u[3] = b1;
        paB = pk.v;
    }
}

__global__ __launch_bounds__(512, 2) void attn(
    const u16* __restrict__ Qb, const u16* __restrict__ Kimg,
    const u16* __restrict__ Vimg, u16* __restrict__ Ob)
{
    __shared__ u16 kbuf[3][8192];      // [32 j][256 d] swizzled, 16KB each
    __shared__ u16 vbuf[3][10240];     // [256 e][40 j] padded, 20KB each
    const int tid  = threadIdx.x;
    const int lane = tid & 63;
    const int wave = tid >> 6;
    const int col  = lane & 31;        // q-row for S, e-col for O
    const int hi   = lane >> 5;
    const int hi8  = hi * 8;
    const int ksw  = (lane & 7) << 3;  // K-read XOR swizzle
    // XCD swizzle: 256 blocks, 32 per XCD -> 8 distinct (b,h) per XCD
    const int bid  = ((blockIdx.x & 7) << 5) | (blockIdx.x >> 3);
    const int bh   = bid >> 2;
    const int qblk = bid & 3;
    const int q0   = qblk * 256 + wave * 32;   // wave's 32 q-rows

    const u16* qp = Qb + ((size_t)bh * 1024 + q0) * 256;
    const u16* kg = Kimg + (size_t)bh * 262144;
    const u16* vg = Vimg + (size_t)bh * 327680;

    // capture-safe role-split stage: waves 0-3 -> K (4 loads), 4-7 -> V (5 loads)
    #define STAGE(sl, t)                                                          \
        {                                                                         \
            const int sl_ = (sl);                                                 \
            const int t_  = (t);                                                  \
            if (tid < 256) {                                                      \
                const size_t kb_ = (size_t)t_ * 8192 + tid * 8;                   \
                _Pragma("unroll")                                                 \
                for (int c_ = 0; c_ < 4; ++c_)                                    \
                    GLOAD16(&kg[kb_ + c_ * 2048], &kbuf[sl_][c_ * 2048 + tid * 8]); \
            } else {                                                              \
                const int    vt_ = tid - 256;                                     \
                const size_t vb_ = (size_t)t_ * 10240 + vt_ * 8;                  \
                _Pragma("unroll")                                                 \
                for (int c_ = 0; c_ < 5; ++c_)                                    \
                    GLOAD16(&vg[vb_ + c_ * 2048], &vbuf[sl_][c_ * 2048 + vt_ * 8]); \
            }                                                                     \
        }

    // Q B-frags first (their vmcnt retires before the batches we count against)
    s16x8 qf[16];
    #pragma unroll
    for (int dk = 0; dk < 16; ++dk)
        qf[dk] = *(const s16x8*)&qp[(size_t)col * 256 + dk * 16 + hi8];

    // prologue: 3 batches in flight
    STAGE(0, 0);
    STAGE(1, 1);
    STAGE(2, 2);

    f32x16 oacc[8] = {};               // O[q=crow(r,hi)][e=et*32+col]
    float m_run = -1e30f, l_run = 0.f;
    f32x16 sacc;
    s16x8 paA, paB;

    for (int i = 0; i < 32; ++i) {
        // counted wait: allow 2 newest batches in flight -> batch i resident
        if (tid < 256) { asm volatile("s_waitcnt vmcnt(8)"  ::: "memory"); }
        else           { asm volatile("s_waitcnt vmcnt(10)" ::: "memory"); }
        __builtin_amdgcn_s_barrier();              // barrier-A: whole tile i visible
        asm volatile("" ::: "memory");
        const int slot = i % 3;
        const u16* kt = kbuf[slot];
        const u16* vt = vbuf[slot];

        __builtin_amdgcn_s_setprio(1);
        {   // QK: S[j=crow(r,hi)][q=col]
            sacc = (f32x16){};
            const int rb_ = col * 256;
            #pragma unroll
            for (int dk_ = 0; dk_ < 16; ++dk_) {
                s16x8 kf = *(const s16x8*)&kt[rb_ + ((dk_ * 16 + hi8) ^ ksw)];
                sacc = __builtin_amdgcn_mfma_f32_32x32x16_bf16(kf, qf[dk_], sacc, 0, 0, 0);
            }
        }
        __builtin_amdgcn_s_setprio(0);

        softmax_pack(sacc, m_run, l_run, oacc, hi, paA, paB);

        __builtin_amdgcn_s_setprio(1);
        {   // PV
            #pragma unroll
            for (int et_ = 0; et_ < 8; ++et_) {
                s16x8 vf = *(const s16x8*)&vt[(et_ * 32 + col) * 40 + hi8];
                oacc[et_] = __builtin_amdgcn_mfma_f32_32x32x16_bf16(paA, vf, oacc[et_], 0, 0, 0);
            }
            #pragma unroll
            for (int et_ = 0; et_ < 8; ++et_) {
                s16x8 vf = *(const s16x8*)&vt[(et_ * 32 + col) * 40 + 16 + hi8];
                oacc[et_] = __builtin_amdgcn_mfma_f32_32x32x16_bf16(paB, vf, oacc[et_], 0, 0, 0);
            }
        }
        __builtin_amdgcn_s_setprio(0);

        asm volatile("" ::: "memory");
        __builtin_amdgcn_s_barrier();              // barrier-B: slot reads done
        asm volatile("" ::: "memory");
        const int nt = (i + 3 < 32) ? (i + 3) : 31;   // clamp keeps count invariant
        STAGE(slot, nt);                           // slot (i+3)%3 == i%3, just freed
    }
    #undef STAGE

    // normalize + store: Ob [B,S,H*256]
    const float linv = 1.0f / l_run;
    const int b = bh >> 3, h = bh & 7;
    u16* op = Ob + ((size_t)b * 1024) * 2048 + h * 256;
    #pragma unroll
    for (int r = 0; r < 16; ++r) {
        const int crow = (r & 3) + 8 * (r >> 2) + 4 * hi;
        float lr = __shfl(linv, crow);
        const size_t row = q0 + crow;
        #pragma unroll
        for (int et = 0; et < 8; ++et)
            op[row * 2048 + et * 32 + col] = f2bf(oacc[et][r] * lr);
    }
}

// ---------------- output projection ----------------
// out[m, n] = sum_k Ob[m, k] * Wp[n, k]; M=8192, N=256, K=2048; fp32 out.
// R13 (validated, -11us): BK=128, 16 iters x 16 MFMAs/wave/iter, 40KB LDS,
// both-sides chunk-XOR swizzle (cl ^ (row&7)).
__global__ __launch_bounds__(256) void out_gemm(
    const u16* __restrict__ Ob, const u16* __restrict__ Wpb, float* __restrict__ out)
{
    __shared__ u16 As[32 * 128];    // [32 m][16 chunks of 8 u16], chunk^row&7
    __shared__ u16 Bs[128 * 128];   // [128 n][16 chunks], chunk^row&7
    const int tid  = threadIdx.x;
    const int lane = tid & 63;
    const int li   = lane & 15, lg = lane >> 4;
    const int wave = tid >> 6;
    const int wr   = wave >> 1, wc = wave & 1;   // wave tile 16x64
    const int m0   = blockIdx.x * 32;
    const int n0   = blockIdx.y * 128;

    f32x4 acc[4] = {};

    for (int k0 = 0; k0 < 2048; k0 += 128) {
        __syncthreads();
        // stage A: 512 16B-chunks, 2 passes (source pre-swizzled, LDS linear)
        #pragma unroll
        for (int p = 0; p < 2; ++p) {
            const int g = p * 256 + tid, row = g >> 4, cl = g & 15;
            GLOAD16(&Ob[(size_t)(m0 + row) * 2048 + k0 + ((cl ^ (row & 7)) * 8)],
                    &As[g * 8]);
        }
        // stage B: 2048 chunks, 8 passes
        #pragma unroll
        for (int p = 0; p < 8; ++p) {
            const int g = p * 256 + tid, row = g >> 4, cl = g & 15;
            GLOAD16(&Wpb[(size_t)(n0 + row) * 2048 + k0 + ((cl ^ (row & 7)) * 8)],
                    &Bs[g * 8]);
        }
        __syncthreads();

        const int arow = wr * 16 + li;
        s16x8 af[4];
        #pragma unroll
        for (int kk = 0; kk < 4; ++kk)
            af[kk] = *(const s16x8*)&As[arow * 128 + (((kk * 4 + lg) ^ (arow & 7)) * 8)];
        #pragma unroll
        for (int ni = 0; ni < 4; ++ni) {
            const int brow = wc * 64 + ni * 16 + li;
            #pragma unroll
            for (int kk = 0; kk < 4; ++kk) {
                s16x8 bf = *(const s16x8*)&Bs[brow * 128 + (((kk * 4 + lg) ^ (brow & 7)) * 8)];
                acc[ni] = __builtin_amdgcn_mfma_f32_16x16x32_bf16(af[kk], bf, acc[ni], 0, 0, 0);
            }
        }
    }

    #pragma unroll
    for (int ni = 0; ni < 4; ++ni) {
        int n = n0 + wc * 64 + ni * 16 + li;
        #pragma unroll
        for (int r = 0; r < 4; ++r) {
            int m = m0 + wr * 16 + lg * 4 + r;
            out[(size_t)m * 256 + n] = acc[ni][r];
        }
    }
}

extern "C" void kernel_launch(void* const* d_in, const int* in_sizes, int n_in,
                              void* d_out, int out_size, void* d_ws, size_t ws_size,
                              hipStream_t stream) {
    const float* x  = (const float*)d_in[0];
    const float* Wq = (const float*)d_in[1];
    const float* Wk = (const float*)d_in[2];
    const float* Wv = (const float*)d_in[3];
    const float* bq = (const float*)d_in[4];
    const float* bk = (const float*)d_in[5];
    const float* bv = (const float*)d_in[6];
    const float* Wp = (const float*)d_in[7];
    float* out = (float*)d_out;

    u16* xb   = (u16*)d_ws;               // 2,097,152
    u16* Wqb  = xb   + (1u << 21);        // 524,288 each
    u16* Wkb  = Wqb  + (1u << 19);
    u16* Wvb  = Wkb  + (1u << 19);
    u16* Wpb  = Wvb  + (1u << 19);
    u16* Qb   = Wpb  + (1u << 19);        // 16,777,216
    u16* Kimg = Qb   + (1u << 24);        // 16,777,216
    u16* Vimg = Kimg + (1u << 24);        // 20,971,520 (padded V)
    u16* Ob   = Vimg + 20971520u;         // 16,777,216

    castall<<<4096, 256, 0, stream>>>(x, Wq, Wk, Wv, Wp, xb, Wqb, Wkb, Wvb, Wpb);
    qkv_gemm<<<dim3(64, 48), 256, 0, stream>>>(xb, Wqb, Wkb, Wvb, bq, bk, bv, Qb, Kimg, Vimg);
    attn<<<256, 512, 0, stream>>>(Qb, Kimg, Vimg, Ob);
    out_gemm<<<dim3(256, 2), 256, 0, stream>>>(Ob, Wpb, out);
}